// Round 1
// baseline (5810.942 us; speedup 1.0000x reference)
//
#include <hip/hip_runtime.h>
#include <hip/hip_bf16.h>

#define N_NODES 100000
#define N_EDGES 1600000

// ---------------- zero fill (capture-safe, no memset) ----------------
__global__ void zero_kernel(float* __restrict__ p, int n4) {
    int i = blockIdx.x * blockDim.x + threadIdx.x;
    if (i < n4) {
        reinterpret_cast<float4*>(p)[i] = make_float4(0.f, 0.f, 0.f, 0.f);
    }
}

// ---------------- degree count ----------------
__global__ void degree_kernel(const int* __restrict__ src, const int* __restrict__ dst,
                              float* __restrict__ outdeg, float* __restrict__ indeg, int E) {
    int i = blockIdx.x * blockDim.x + threadIdx.x;
    if (i < E) {
        atomicAdd(&outdeg[src[i]], 1.0f);
        atomicAdd(&indeg[dst[i]], 1.0f);
    }
}

// deg -> clip(deg,1)^-0.5 in place, over both arrays flat (2N floats)
__global__ void norm_kernel(float* __restrict__ p, int n) {
    int i = blockIdx.x * blockDim.x + threadIdx.x;
    if (i < n) {
        p[i] = rsqrtf(fmaxf(p[i], 1.0f));
    }
}

// ---------------- SGEMM with fused row scaling ----------------
// C[m, 0:128] = rowscale[m] * sum_k A[m,k] * W[k, 0:128]
template<int K>
__global__ __launch_bounds__(256) void gemm_rowscale(
    const float* __restrict__ A,        // [M, K]
    const float* __restrict__ W,        // [K, 128]
    const float* __restrict__ rowscale, // [M]
    float* __restrict__ C,              // [M, 128]
    int M)
{
    constexpr int BM = 64, BN = 128, BK = 32;
    __shared__ float As[BK][BM + 1];   // transposed A tile, +1 pad -> conflict-free writes
    __shared__ float Bs[BK][BN];       // unpadded -> aligned float4 reads

    const int bm = blockIdx.x * BM;
    const int tid = threadIdx.x;
    const int tc = tid & 31;   // col group: 32 groups of 4 cols
    const int tr = tid >> 5;   // row group: 8 groups of 8 rows

    float acc[8][4] = {};

    for (int k0 = 0; k0 < K; k0 += BK) {
        // A tile: 64x32 elems, 8 per thread, coalesced along k
        #pragma unroll
        for (int i = 0; i < 8; ++i) {
            int lin = tid + i * 256;
            int r = lin >> 5, c = lin & 31;
            int row = bm + r;
            As[c][r] = (row < M) ? A[(size_t)row * K + (k0 + c)] : 0.0f;
        }
        // B tile: 32x128 elems, float4 loads, 4 per thread
        #pragma unroll
        for (int i = 0; i < 4; ++i) {
            int lin = (tid + i * 256) * 4;
            int r = lin >> 7, c = lin & 127;
            float4 v = *reinterpret_cast<const float4*>(&W[(size_t)(k0 + r) * 128 + c]);
            *reinterpret_cast<float4*>(&Bs[r][c]) = v;
        }
        __syncthreads();

        #pragma unroll
        for (int kk = 0; kk < BK; ++kk) {
            float a[8], b[4];
            #pragma unroll
            for (int i = 0; i < 8; ++i) a[i] = As[kk][tr * 8 + i];   // broadcast reads
            float4 bv = *reinterpret_cast<const float4*>(&Bs[kk][tc * 4]);
            b[0] = bv.x; b[1] = bv.y; b[2] = bv.z; b[3] = bv.w;
            #pragma unroll
            for (int i = 0; i < 8; ++i)
                #pragma unroll
                for (int j = 0; j < 4; ++j)
                    acc[i][j] += a[i] * b[j];
        }
        __syncthreads();
    }

    #pragma unroll
    for (int i = 0; i < 8; ++i) {
        int row = bm + tr * 8 + i;
        if (row < M) {
            float s = rowscale[row];
            float4 v = make_float4(acc[i][0] * s, acc[i][1] * s, acc[i][2] * s, acc[i][3] * s);
            *reinterpret_cast<float4*>(&C[(size_t)row * 128 + tc * 4]) = v;
        }
    }
}

// ---------------- gather + scatter-add aggregation ----------------
// agg[dst[e], :] += h[src[e], :]   (128 floats per edge; 32 threads/edge, 4 floats/thread)
__global__ void scatter_add_kernel(const float* __restrict__ h,
                                   const int* __restrict__ src,
                                   const int* __restrict__ dst,
                                   float* __restrict__ agg, int E) {
    long long tid = (long long)blockIdx.x * blockDim.x + threadIdx.x;
    int e = (int)(tid >> 5);
    if (e >= E) return;
    int c = ((int)tid & 31) * 4;
    int s = src[e];
    int d = dst[e];
    float4 v = *reinterpret_cast<const float4*>(&h[(size_t)s * 128 + c]);
    float* p = &agg[(size_t)d * 128 + c];
    atomicAdd(p + 0, v.x);
    atomicAdd(p + 1, v.y);
    atomicAdd(p + 2, v.z);
    atomicAdd(p + 3, v.w);
}

// ---------------- epilogue: out = relu(agg * norm_dst + b) ----------------
__global__ void epilogue_kernel(const float* __restrict__ agg,
                                const float* __restrict__ ndst,
                                const float* __restrict__ bias,
                                float* __restrict__ out, int N) {
    long long tid = (long long)blockIdx.x * blockDim.x + threadIdx.x;
    int n = (int)(tid >> 5);
    if (n >= N) return;
    int c = ((int)tid & 31) * 4;
    float s = ndst[n];
    float4 a = *reinterpret_cast<const float4*>(&agg[(size_t)n * 128 + c]);
    float4 b = *reinterpret_cast<const float4*>(&bias[c]);
    float4 r;
    r.x = fmaxf(a.x * s + b.x, 0.f);
    r.y = fmaxf(a.y * s + b.y, 0.f);
    r.z = fmaxf(a.z * s + b.z, 0.f);
    r.w = fmaxf(a.w * s + b.w, 0.f);
    *reinterpret_cast<float4*>(&out[(size_t)n * 128 + c]) = r;
}

extern "C" void kernel_launch(void* const* d_in, const int* in_sizes, int n_in,
                              void* d_out, int out_size, void* d_ws, size_t ws_size,
                              hipStream_t stream) {
    const float* feat = (const float*)d_in[0];   // [1, N, 256]
    const float* W1   = (const float*)d_in[1];   // [256, 128]
    const float* b1   = (const float*)d_in[2];   // [128]
    const float* W2   = (const float*)d_in[3];   // [128, 128]
    const float* b2   = (const float*)d_in[4];   // [128]
    const int* esrc   = (const int*)d_in[5];     // [E]
    const int* edst   = (const int*)d_in[6];     // [E]
    float* out = (float*)d_out;                  // [N, 128]

    const int Nn = N_NODES, E = N_EDGES;

    // workspace layout (all f32): nsrc[N] | ndst[N] | h[N*128] | agg[N*128]
    float* nsrc = (float*)d_ws;
    float* ndst = nsrc + Nn;
    float* h    = ndst + Nn;
    float* agg  = h + (size_t)Nn * 128;

    const int feat_elems = Nn * 128;             // per h/agg buffer
    const int agg_blocks = (feat_elems / 4 + 255) / 256;

    // --- norms ---
    zero_kernel<<<((2 * Nn) / 4 + 255) / 256, 256, 0, stream>>>(nsrc, (2 * Nn) / 4);
    degree_kernel<<<(E + 255) / 256, 256, 0, stream>>>(esrc, edst, nsrc, ndst, E);
    norm_kernel<<<(2 * Nn + 255) / 256, 256, 0, stream>>>(nsrc, 2 * Nn);

    // --- layer 1 ---
    gemm_rowscale<256><<<(Nn + 63) / 64, 256, 0, stream>>>(feat, W1, nsrc, h, Nn);
    zero_kernel<<<agg_blocks, 256, 0, stream>>>(agg, feat_elems / 4);
    scatter_add_kernel<<<(int)(((long long)E * 32 + 255) / 256), 256, 0, stream>>>(h, esrc, edst, agg, E);
    epilogue_kernel<<<(int)(((long long)Nn * 32 + 255) / 256), 256, 0, stream>>>(agg, ndst, b1, h, Nn);

    // --- layer 2 (d_out doubles as GEMM temp) ---
    gemm_rowscale<128><<<(Nn + 63) / 64, 256, 0, stream>>>(h, W2, nsrc, out, Nn);
    zero_kernel<<<agg_blocks, 256, 0, stream>>>(agg, feat_elems / 4);
    scatter_add_kernel<<<(int)(((long long)E * 32 + 255) / 256), 256, 0, stream>>>(out, esrc, edst, agg, E);
    epilogue_kernel<<<(int)(((long long)Nn * 32 + 255) / 256), 256, 0, stream>>>(agg, ndst, b2, out, Nn);
}

// Round 2
// 698.439 us; speedup vs baseline: 8.3199x; 8.3199x over previous
//
#include <hip/hip_runtime.h>
#include <hip/hip_bf16.h>

#define N_NODES 100000
#define N_EDGES 1600000

// ---------------- zero fill for ints ----------------
__global__ void zero_int_kernel(int* __restrict__ p, int n4) {
    int i = blockIdx.x * blockDim.x + threadIdx.x;
    if (i < n4) {
        reinterpret_cast<int4*>(p)[i] = make_int4(0, 0, 0, 0);
    }
}

// ---------------- degree histograms (int) ----------------
__global__ void hist_kernel(const int* __restrict__ src, const int* __restrict__ dst,
                            int* __restrict__ cnt_src, int* __restrict__ cnt_dst, int E) {
    int i = blockIdx.x * blockDim.x + threadIdx.x;
    if (i < E) {
        atomicAdd(&cnt_src[src[i]], 1);
        atomicAdd(&cnt_dst[dst[i]], 1);
    }
}

// norms: n[i] = clip(deg,1)^-0.5
__global__ void norm_kernel(const int* __restrict__ cnt_src, const int* __restrict__ cnt_dst,
                            float* __restrict__ nsrc, float* __restrict__ ndst, int n) {
    int i = blockIdx.x * blockDim.x + threadIdx.x;
    if (i < n) {
        nsrc[i] = rsqrtf(fmaxf((float)cnt_src[i], 1.0f));
        ndst[i] = rsqrtf(fmaxf((float)cnt_dst[i], 1.0f));
    }
}

// ---------------- exclusive scan (3-phase) ----------------
__global__ __launch_bounds__(1024) void scan_blocks(const int* __restrict__ counts,
                                                    int* __restrict__ rowptr,
                                                    int* __restrict__ partials, int n) {
    __shared__ int tmp[1024];
    int i = blockIdx.x * 1024 + threadIdx.x;
    int v = (i < n) ? counts[i] : 0;
    tmp[threadIdx.x] = v;
    __syncthreads();
    for (int off = 1; off < 1024; off <<= 1) {
        int t = (threadIdx.x >= (unsigned)off) ? tmp[threadIdx.x - off] : 0;
        __syncthreads();
        tmp[threadIdx.x] += t;
        __syncthreads();
    }
    if (i < n) rowptr[i] = tmp[threadIdx.x] - v;  // exclusive
    if (threadIdx.x == 1023) partials[blockIdx.x] = tmp[1023];
}

__global__ void scan_partials(int* __restrict__ partials, int nb) {
    if (threadIdx.x == 0 && blockIdx.x == 0) {
        int s = 0;
        for (int b = 0; b < nb; ++b) { int t = partials[b]; partials[b] = s; s += t; }
    }
}

__global__ void add_offsets(int* __restrict__ rowptr, const int* __restrict__ partials,
                            int* __restrict__ cursor, int n, int total) {
    int i = blockIdx.x * blockDim.x + threadIdx.x;
    if (i < n) {
        int v = rowptr[i] + partials[i >> 10];
        rowptr[i] = v;
        cursor[i] = v;
    }
    if (i == 0) rowptr[n] = total;
}

// ---------------- CSR fill: csr_src sorted by dst ----------------
__global__ void fill_csr_kernel(const int* __restrict__ src, const int* __restrict__ dst,
                                int* __restrict__ cursor, int* __restrict__ csr_src, int E) {
    int i = blockIdx.x * blockDim.x + threadIdx.x;
    if (i < E) {
        int pos = atomicAdd(&cursor[dst[i]], 1);
        csr_src[pos] = src[i];
    }
}

// ---------------- SGEMM with fused row scaling ----------------
// C[m, 0:128] = rowscale[m] * sum_k A[m,k] * W[k, 0:128]
template<int K>
__global__ __launch_bounds__(256) void gemm_rowscale(
    const float* __restrict__ A,        // [M, K]
    const float* __restrict__ W,        // [K, 128]
    const float* __restrict__ rowscale, // [M]
    float* __restrict__ C,              // [M, 128]
    int M)
{
    constexpr int BM = 64, BN = 128, BK = 32;
    __shared__ float As[BK][BM + 1];
    __shared__ float Bs[BK][BN];

    const int bm = blockIdx.x * BM;
    const int tid = threadIdx.x;
    const int tc = tid & 31;
    const int tr = tid >> 5;

    float acc[8][4] = {};

    for (int k0 = 0; k0 < K; k0 += BK) {
        #pragma unroll
        for (int i = 0; i < 8; ++i) {
            int lin = tid + i * 256;
            int r = lin >> 5, c = lin & 31;
            int row = bm + r;
            As[c][r] = (row < M) ? A[(size_t)row * K + (k0 + c)] : 0.0f;
        }
        #pragma unroll
        for (int i = 0; i < 4; ++i) {
            int lin = (tid + i * 256) * 4;
            int r = lin >> 7, c = lin & 127;
            float4 v = *reinterpret_cast<const float4*>(&W[(size_t)(k0 + r) * 128 + c]);
            *reinterpret_cast<float4*>(&Bs[r][c]) = v;
        }
        __syncthreads();

        #pragma unroll
        for (int kk = 0; kk < BK; ++kk) {
            float a[8], b[4];
            #pragma unroll
            for (int i = 0; i < 8; ++i) a[i] = As[kk][tr * 8 + i];
            float4 bv = *reinterpret_cast<const float4*>(&Bs[kk][tc * 4]);
            b[0] = bv.x; b[1] = bv.y; b[2] = bv.z; b[3] = bv.w;
            #pragma unroll
            for (int i = 0; i < 8; ++i)
                #pragma unroll
                for (int j = 0; j < 4; ++j)
                    acc[i][j] += a[i] * b[j];
        }
        __syncthreads();
    }

    #pragma unroll
    for (int i = 0; i < 8; ++i) {
        int row = bm + tr * 8 + i;
        if (row < M) {
            float s = rowscale[row];
            float4 v = make_float4(acc[i][0] * s, acc[i][1] * s, acc[i][2] * s, acc[i][3] * s);
            *reinterpret_cast<float4*>(&C[(size_t)row * 128 + tc * 4]) = v;
        }
    }
}

// ---------------- CSR aggregation, fused epilogue ----------------
// out[n,:] = relu( (sum_{e in in(n)} h[csr_src[e],:]) * ndst[n] + bias )
__global__ void aggregate_kernel(const float* __restrict__ h,
                                 const int* __restrict__ rowptr,
                                 const int* __restrict__ csr_src,
                                 const float* __restrict__ ndst,
                                 const float* __restrict__ bias,
                                 float* __restrict__ out, int N) {
    long long tid = (long long)blockIdx.x * blockDim.x + threadIdx.x;
    int node = (int)(tid >> 5);
    if (node >= N) return;
    int c = ((int)tid & 31) * 4;
    int beg = rowptr[node];
    int end = rowptr[node + 1];
    float4 acc = make_float4(0.f, 0.f, 0.f, 0.f);
    for (int j = beg; j < end; ++j) {
        int s = csr_src[j];
        float4 v = *reinterpret_cast<const float4*>(&h[(size_t)s * 128 + c]);
        acc.x += v.x; acc.y += v.y; acc.z += v.z; acc.w += v.w;
    }
    float sc = ndst[node];
    float4 b = *reinterpret_cast<const float4*>(&bias[c]);
    float4 r;
    r.x = fmaxf(acc.x * sc + b.x, 0.f);
    r.y = fmaxf(acc.y * sc + b.y, 0.f);
    r.z = fmaxf(acc.z * sc + b.z, 0.f);
    r.w = fmaxf(acc.w * sc + b.w, 0.f);
    *reinterpret_cast<float4*>(&out[(size_t)node * 128 + c]) = r;
}

extern "C" void kernel_launch(void* const* d_in, const int* in_sizes, int n_in,
                              void* d_out, int out_size, void* d_ws, size_t ws_size,
                              hipStream_t stream) {
    const float* feat = (const float*)d_in[0];   // [1, N, 256]
    const float* W1   = (const float*)d_in[1];   // [256, 128]
    const float* b1   = (const float*)d_in[2];   // [128]
    const float* W2   = (const float*)d_in[3];   // [128, 128]
    const float* b2   = (const float*)d_in[4];   // [128]
    const int* esrc   = (const int*)d_in[5];     // [E]
    const int* edst   = (const int*)d_in[6];     // [E]
    float* out = (float*)d_out;                  // [N, 128]

    const int Nn = N_NODES, E = N_EDGES;
    const int NB = (Nn + 1023) / 1024;           // scan blocks = 98

    // workspace layout:
    // h[N*128] f32 | csr_src[E] | rowptr[N+1] | partials[NB] | cnt_src[N] | cnt_dst[N] | nsrc[N] | ndst[N]
    float* h      = (float*)d_ws;
    int* csr_src  = (int*)(h + (size_t)Nn * 128);
    int* rowptr   = csr_src + E;
    int* partials = rowptr + (Nn + 1);
    int* cnt_src  = partials + ((NB + 3) & ~3);
    int* cnt_dst  = cnt_src + Nn;
    float* nsrc   = (float*)(cnt_dst + Nn);
    float* ndst   = nsrc + Nn;
    int* cursor   = cnt_src;                     // alias: cnt_src dead after norm_kernel

    // --- degrees & norms ---
    zero_int_kernel<<<(2 * Nn / 4 + 255) / 256, 256, 0, stream>>>(cnt_src, 2 * Nn / 4);
    hist_kernel<<<(E + 255) / 256, 256, 0, stream>>>(esrc, edst, cnt_src, cnt_dst, E);
    norm_kernel<<<(Nn + 255) / 256, 256, 0, stream>>>(cnt_src, cnt_dst, nsrc, ndst, Nn);

    // --- CSR build (sorted by dst) ---
    scan_blocks<<<NB, 1024, 0, stream>>>(cnt_dst, rowptr, partials, Nn);
    scan_partials<<<1, 64, 0, stream>>>(partials, NB);
    add_offsets<<<(Nn + 255) / 256, 256, 0, stream>>>(rowptr, partials, cursor, Nn, E);
    fill_csr_kernel<<<(E + 255) / 256, 256, 0, stream>>>(esrc, edst, cursor, csr_src, E);

    // --- layer 1: gemm -> h; aggregate -> d_out ---
    gemm_rowscale<256><<<(Nn + 63) / 64, 256, 0, stream>>>(feat, W1, nsrc, h, Nn);
    aggregate_kernel<<<(int)(((long long)Nn * 32 + 255) / 256), 256, 0, stream>>>(
        h, rowptr, csr_src, ndst, b1, out, Nn);

    // --- layer 2: gemm (reads d_out) -> h; aggregate -> d_out ---
    gemm_rowscale<128><<<(Nn + 63) / 64, 256, 0, stream>>>(out, W2, nsrc, h, Nn);
    aggregate_kernel<<<(int)(((long long)Nn * 32 + 255) / 256), 256, 0, stream>>>(
        h, rowptr, csr_src, ndst, b2, out, Nn);
}

// Round 3
// 592.993 us; speedup vs baseline: 9.7993x; 1.1778x over previous
//
#include <hip/hip_runtime.h>
#include <hip/hip_bf16.h>

#define N_NODES 100000
#define N_EDGES 1600000

typedef __bf16 bf16x8 __attribute__((ext_vector_type(8)));
typedef float f32x4 __attribute__((ext_vector_type(4)));
typedef unsigned short u16x8 __attribute__((ext_vector_type(8)));

// ---------------- helpers: f32 -> bf16 (RNE) split ----------------
__device__ __forceinline__ unsigned short f32_to_bf16_rne(float x) {
    unsigned int u = __float_as_uint(x);
    unsigned int r = u + 0x7FFFu + ((u >> 16) & 1u);
    return (unsigned short)(r >> 16);
}
__device__ __forceinline__ float bf16_bits_to_f32(unsigned short h) {
    return __uint_as_float(((unsigned int)h) << 16);
}

// ---------------- zero fill for ints ----------------
__global__ void zero_int_kernel(int* __restrict__ p, int n4) {
    int i = blockIdx.x * blockDim.x + threadIdx.x;
    if (i < n4) {
        reinterpret_cast<int4*>(p)[i] = make_int4(0, 0, 0, 0);
    }
}

// ---------------- degree histograms (int) ----------------
__global__ void hist_kernel(const int* __restrict__ src, const int* __restrict__ dst,
                            int* __restrict__ cnt_src, int* __restrict__ cnt_dst, int E) {
    int i = blockIdx.x * blockDim.x + threadIdx.x;
    if (i < E) {
        atomicAdd(&cnt_src[src[i]], 1);
        atomicAdd(&cnt_dst[dst[i]], 1);
    }
}

// norms: n[i] = clip(deg,1)^-0.5
__global__ void norm_kernel(const int* __restrict__ cnt_src, const int* __restrict__ cnt_dst,
                            float* __restrict__ nsrc, float* __restrict__ ndst, int n) {
    int i = blockIdx.x * blockDim.x + threadIdx.x;
    if (i < n) {
        nsrc[i] = rsqrtf(fmaxf((float)cnt_src[i], 1.0f));
        ndst[i] = rsqrtf(fmaxf((float)cnt_dst[i], 1.0f));
    }
}

// ---------------- exclusive scan (3-phase) ----------------
__global__ __launch_bounds__(1024) void scan_blocks(const int* __restrict__ counts,
                                                    int* __restrict__ rowptr,
                                                    int* __restrict__ partials, int n) {
    __shared__ int tmp[1024];
    int i = blockIdx.x * 1024 + threadIdx.x;
    int v = (i < n) ? counts[i] : 0;
    tmp[threadIdx.x] = v;
    __syncthreads();
    for (int off = 1; off < 1024; off <<= 1) {
        int t = (threadIdx.x >= (unsigned)off) ? tmp[threadIdx.x - off] : 0;
        __syncthreads();
        tmp[threadIdx.x] += t;
        __syncthreads();
    }
    if (i < n) rowptr[i] = tmp[threadIdx.x] - v;  // exclusive
    if (threadIdx.x == 1023) partials[blockIdx.x] = tmp[1023];
}

__global__ void scan_partials(int* __restrict__ partials, int nb) {
    if (threadIdx.x == 0 && blockIdx.x == 0) {
        int s = 0;
        for (int b = 0; b < nb; ++b) { int t = partials[b]; partials[b] = s; s += t; }
    }
}

__global__ void add_offsets(int* __restrict__ rowptr, const int* __restrict__ partials,
                            int* __restrict__ cursor, int n, int total) {
    int i = blockIdx.x * blockDim.x + threadIdx.x;
    if (i < n) {
        int v = rowptr[i] + partials[i >> 10];
        rowptr[i] = v;
        cursor[i] = v;
    }
    if (i == 0) rowptr[n] = total;
}

// ---------------- CSR fill: csr_src sorted by dst ----------------
__global__ void fill_csr_kernel(const int* __restrict__ src, const int* __restrict__ dst,
                                int* __restrict__ cursor, int* __restrict__ csr_src, int E) {
    int i = blockIdx.x * blockDim.x + threadIdx.x;
    if (i < E) {
        int pos = atomicAdd(&cursor[dst[i]], 1);
        csr_src[pos] = src[i];
    }
}

// ---------------- W -> W^T split into bf16 hi/lo ----------------
// WTh/WTl are [128][K] (col-major view of W[K][128])
template<int K>
__global__ void wtsplit_kernel(const float* __restrict__ W,
                               unsigned short* __restrict__ WTh,
                               unsigned short* __restrict__ WTl) {
    int i = blockIdx.x * blockDim.x + threadIdx.x;  // 128*K total
    if (i < 128 * K) {
        int col = i / K, k = i % K;
        float x = W[(size_t)k * 128 + col];
        unsigned short h = f32_to_bf16_rne(x);
        unsigned short l = f32_to_bf16_rne(x - bf16_bits_to_f32(h));
        WTh[i] = h;
        WTl[i] = l;
    }
}

// ---------------- MFMA GEMM (bf16 3-term split) with fused row scaling ----
// C[m, 0:128] = rowscale[m] * sum_k A[m,k] * W[k, 0:128]
// Block: 256 threads = 4 waves in 2x2; tile BM=128, BN=128, BK=64.
template<int K>
__global__ __launch_bounds__(256) void gemm_mfma(
    const float* __restrict__ A,            // [M, K] f32
    const unsigned short* __restrict__ WTh, // [128][K] bf16 hi
    const unsigned short* __restrict__ WTl, // [128][K] bf16 lo
    const float* __restrict__ rowscale,     // [M]
    float* __restrict__ C,                  // [M, 128]
    int M)
{
    // LDS: 4 arrays x [128][64] ushort = 16 KB each = 64 KB total
    __shared__ unsigned short Ah[128 * 64];
    __shared__ unsigned short Al[128 * 64];
    __shared__ unsigned short Bh[128 * 64];
    __shared__ unsigned short Bl[128 * 64];

    const int tid = threadIdx.x;
    const int bm = blockIdx.x * 128;
    const int lane = tid & 63;
    const int wid = tid >> 6;        // 0..3
    const int wm = wid >> 1;         // 0..1 (row half)
    const int wn = wid & 1;          // 0..1 (col half)
    const int lr = lane & 15;        // fragment row/col index
    const int lg = lane >> 4;        // k-group 0..3

    f32x4 acc[4][4];
    #pragma unroll
    for (int i = 0; i < 4; ++i)
        #pragma unroll
        for (int j = 0; j < 4; ++j)
            acc[i][j] = (f32x4){0.f, 0.f, 0.f, 0.f};

    for (int k0 = 0; k0 < K; k0 += 64) {
        // ---- stage A tile: 128 rows x 64 k, f32 -> bf16 hi/lo ----
        #pragma unroll
        for (int i = 0; i < 4; ++i) {
            int lin = tid + i * 256;     // 0..1023
            int row = lin >> 3;          // 0..127
            int s8  = lin & 7;           // k-slot (8 elems)
            int rg  = bm + row;
            float v[8];
            if (rg < M) {
                const float* ap = &A[(size_t)rg * K + k0 + s8 * 8];
                float4 v0 = *reinterpret_cast<const float4*>(ap);
                float4 v1 = *reinterpret_cast<const float4*>(ap + 4);
                v[0] = v0.x; v[1] = v0.y; v[2] = v0.z; v[3] = v0.w;
                v[4] = v1.x; v[5] = v1.y; v[6] = v1.z; v[7] = v1.w;
            } else {
                #pragma unroll
                for (int j = 0; j < 8; ++j) v[j] = 0.f;
            }
            u16x8 vh, vl;
            #pragma unroll
            for (int j = 0; j < 8; ++j) {
                unsigned short h = f32_to_bf16_rne(v[j]);
                vh[j] = h;
                vl[j] = f32_to_bf16_rne(v[j] - bf16_bits_to_f32(h));
            }
            int off = row * 64 + ((s8 ^ (row & 7)) << 3);  // ushort units
            *reinterpret_cast<u16x8*>(&Ah[off]) = vh;
            *reinterpret_cast<u16x8*>(&Al[off]) = vl;
        }
        // ---- stage B tile: 128 cols x 64 k from WT (already bf16) ----
        #pragma unroll
        for (int i = 0; i < 4; ++i) {
            int lin = tid + i * 256;
            int col = lin >> 3;
            int s8  = lin & 7;
            const size_t g = (size_t)col * K + k0 + s8 * 8;
            u16x8 vh = *reinterpret_cast<const u16x8*>(&WTh[g]);
            u16x8 vl = *reinterpret_cast<const u16x8*>(&WTl[g]);
            int off = col * 64 + ((s8 ^ (col & 7)) << 3);
            *reinterpret_cast<u16x8*>(&Bh[off]) = vh;
            *reinterpret_cast<u16x8*>(&Bl[off]) = vl;
        }
        __syncthreads();

        // ---- MFMA over 2 k-substeps of 32 ----
        #pragma unroll
        for (int ks = 0; ks < 2; ++ks) {
            const int s8 = ks * 4 + lg;   // k-slot for this lane group
            bf16x8 afh[4], afl[4], bfh[4], bfl[4];
            #pragma unroll
            for (int mt = 0; mt < 4; ++mt) {
                int row = wm * 64 + mt * 16 + lr;
                int off = row * 64 + ((s8 ^ (row & 7)) << 3);
                afh[mt] = *reinterpret_cast<const bf16x8*>(&Ah[off]);
                afl[mt] = *reinterpret_cast<const bf16x8*>(&Al[off]);
            }
            #pragma unroll
            for (int nt = 0; nt < 4; ++nt) {
                int col = wn * 64 + nt * 16 + lr;
                int off = col * 64 + ((s8 ^ (col & 7)) << 3);
                bfh[nt] = *reinterpret_cast<const bf16x8*>(&Bh[off]);
                bfl[nt] = *reinterpret_cast<const bf16x8*>(&Bl[off]);
            }
            #pragma unroll
            for (int mt = 0; mt < 4; ++mt) {
                #pragma unroll
                for (int nt = 0; nt < 4; ++nt) {
                    acc[mt][nt] = __builtin_amdgcn_mfma_f32_16x16x32_bf16(
                        afh[mt], bfh[nt], acc[mt][nt], 0, 0, 0);
                    acc[mt][nt] = __builtin_amdgcn_mfma_f32_16x16x32_bf16(
                        afh[mt], bfl[nt], acc[mt][nt], 0, 0, 0);
                    acc[mt][nt] = __builtin_amdgcn_mfma_f32_16x16x32_bf16(
                        afl[mt], bfh[nt], acc[mt][nt], 0, 0, 0);
                }
            }
        }
        __syncthreads();
    }

    // ---- epilogue: scale rows, store ----
    // D mapping: col = lane&15, row = (lane>>4)*4 + r
    #pragma unroll
    for (int mt = 0; mt < 4; ++mt) {
        #pragma unroll
        for (int r = 0; r < 4; ++r) {
            int row = bm + wm * 64 + mt * 16 + lg * 4 + r;
            if (row < M) {
                float s = rowscale[row];
                #pragma unroll
                for (int nt = 0; nt < 4; ++nt) {
                    int col = wn * 64 + nt * 16 + lr;
                    C[(size_t)row * 128 + col] = acc[mt][nt][r] * s;
                }
            }
        }
    }
}

// ---------------- CSR aggregation, fused epilogue ----------------
// out[n,:] = relu( (sum_{e in in(n)} h[csr_src[e],:]) * ndst[n] + bias )
__global__ void aggregate_kernel(const float* __restrict__ h,
                                 const int* __restrict__ rowptr,
                                 const int* __restrict__ csr_src,
                                 const float* __restrict__ ndst,
                                 const float* __restrict__ bias,
                                 float* __restrict__ out, int N) {
    long long tid = (long long)blockIdx.x * blockDim.x + threadIdx.x;
    int node = (int)(tid >> 5);
    if (node >= N) return;
    int c = ((int)tid & 31) * 4;
    int beg = rowptr[node];
    int end = rowptr[node + 1];
    float4 acc = make_float4(0.f, 0.f, 0.f, 0.f);
    for (int j = beg; j < end; ++j) {
        int s = csr_src[j];
        float4 v = *reinterpret_cast<const float4*>(&h[(size_t)s * 128 + c]);
        acc.x += v.x; acc.y += v.y; acc.z += v.z; acc.w += v.w;
    }
    float sc = ndst[node];
    float4 b = *reinterpret_cast<const float4*>(&bias[c]);
    float4 r;
    r.x = fmaxf(acc.x * sc + b.x, 0.f);
    r.y = fmaxf(acc.y * sc + b.y, 0.f);
    r.z = fmaxf(acc.z * sc + b.z, 0.f);
    r.w = fmaxf(acc.w * sc + b.w, 0.f);
    *reinterpret_cast<float4*>(&out[(size_t)node * 128 + c]) = r;
}

extern "C" void kernel_launch(void* const* d_in, const int* in_sizes, int n_in,
                              void* d_out, int out_size, void* d_ws, size_t ws_size,
                              hipStream_t stream) {
    const float* feat = (const float*)d_in[0];   // [1, N, 256]
    const float* W1   = (const float*)d_in[1];   // [256, 128]
    const float* b1   = (const float*)d_in[2];   // [128]
    const float* W2   = (const float*)d_in[3];   // [128, 128]
    const float* b2   = (const float*)d_in[4];   // [128]
    const int* esrc   = (const int*)d_in[5];     // [E]
    const int* edst   = (const int*)d_in[6];     // [E]
    float* out = (float*)d_out;                  // [N, 128]

    const int Nn = N_NODES, E = N_EDGES;
    const int NB = (Nn + 1023) / 1024;           // scan blocks = 98

    // workspace layout:
    // h[N*128] f32 | csr_src[E] | rowptr[N+1] | partials[NB] | cnt_src[N] | cnt_dst[N]
    // | nsrc[N] | ndst[N] | WT1h[128*256] | WT1l | WT2h[128*128] | WT2l   (ushort)
    float* h      = (float*)d_ws;
    int* csr_src  = (int*)(h + (size_t)Nn * 128);
    int* rowptr   = csr_src + E;
    int* partials = rowptr + (Nn + 1);
    int* cnt_src  = partials + ((NB + 3) & ~3);
    int* cnt_dst  = cnt_src + Nn;
    float* nsrc   = (float*)(cnt_dst + Nn);
    float* ndst   = nsrc + Nn;
    unsigned short* WT1h = (unsigned short*)(ndst + Nn);
    unsigned short* WT1l = WT1h + 128 * 256;
    unsigned short* WT2h = WT1l + 128 * 256;
    unsigned short* WT2l = WT2h + 128 * 128;
    int* cursor   = cnt_src;                     // alias: cnt_src dead after norm_kernel

    // --- weight transpose+split (tiny) ---
    wtsplit_kernel<256><<<(128 * 256 + 255) / 256, 256, 0, stream>>>(W1, WT1h, WT1l);
    wtsplit_kernel<128><<<(128 * 128 + 255) / 256, 256, 0, stream>>>(W2, WT2h, WT2l);

    // --- degrees & norms ---
    zero_int_kernel<<<(2 * Nn / 4 + 255) / 256, 256, 0, stream>>>(cnt_src, 2 * Nn / 4);
    hist_kernel<<<(E + 255) / 256, 256, 0, stream>>>(esrc, edst, cnt_src, cnt_dst, E);
    norm_kernel<<<(Nn + 255) / 256, 256, 0, stream>>>(cnt_src, cnt_dst, nsrc, ndst, Nn);

    // --- CSR build (sorted by dst) ---
    scan_blocks<<<NB, 1024, 0, stream>>>(cnt_dst, rowptr, partials, Nn);
    scan_partials<<<1, 64, 0, stream>>>(partials, NB);
    add_offsets<<<(Nn + 255) / 256, 256, 0, stream>>>(rowptr, partials, cursor, Nn, E);
    fill_csr_kernel<<<(E + 255) / 256, 256, 0, stream>>>(esrc, edst, cursor, csr_src, E);

    // --- layer 1: gemm -> h; aggregate -> d_out ---
    gemm_mfma<256><<<(Nn + 127) / 128, 256, 0, stream>>>(feat, WT1h, WT1l, nsrc, h, Nn);
    aggregate_kernel<<<(int)(((long long)Nn * 32 + 255) / 256), 256, 0, stream>>>(
        h, rowptr, csr_src, ndst, b1, out, Nn);

    // --- layer 2: gemm (reads d_out) -> h; aggregate -> d_out ---
    gemm_mfma<128><<<(Nn + 127) / 128, 256, 0, stream>>>(out, WT2h, WT2l, nsrc, h, Nn);
    aggregate_kernel<<<(int)(((long long)Nn * 32 + 255) / 256), 256, 0, stream>>>(
        h, rowptr, csr_src, ndst, b2, out, Nn);
}

// Round 4
// 414.317 us; speedup vs baseline: 14.0254x; 1.4313x over previous
//
#include <hip/hip_runtime.h>
#include <hip/hip_bf16.h>

#define N_NODES 100000
#define N_EDGES 1600000
#define NBUCK 391          // ceil(N_NODES / 256)
#define NBLK 256           // bucket-phase blocks
#define CHUNK (N_EDGES / NBLK)   // 6250, exact
#define MATP (NBUCK * NBLK)      // 100096, per-part count-matrix size

typedef __bf16 bf16x8 __attribute__((ext_vector_type(8)));
typedef float f32x4 __attribute__((ext_vector_type(4)));
typedef unsigned short u16x8 __attribute__((ext_vector_type(8)));

// ---------------- helpers: f32 -> bf16 (RNE) split ----------------
__device__ __forceinline__ unsigned short f32_to_bf16_rne(float x) {
    unsigned int u = __float_as_uint(x);
    unsigned int r = u + 0x7FFFu + ((u >> 16) & 1u);
    return (unsigned short)(r >> 16);
}
__device__ __forceinline__ float bf16_bits_to_f32(unsigned short h) {
    return __uint_as_float(((unsigned int)h) << 16);
}

// ---------------- phase 1: coarse bucket histograms (LDS atomics only) ----
__global__ __launch_bounds__(256) void bucket_count(const int* __restrict__ esrc,
                                                    const int* __restrict__ edst,
                                                    int* __restrict__ cnt_mat) {
    __shared__ int hd[NBUCK], hs[NBUCK];
    const int b = blockIdx.x, t = threadIdx.x;
    for (int i = t; i < NBUCK; i += 256) { hd[i] = 0; hs[i] = 0; }
    __syncthreads();
    const int e1 = (b + 1) * CHUNK;
    for (int e = b * CHUNK + t; e < e1; e += 256) {
        atomicAdd(&hd[edst[e] >> 8], 1);
        atomicAdd(&hs[esrc[e] >> 8], 1);
    }
    __syncthreads();
    for (int i = t; i < NBUCK; i += 256) {
        cnt_mat[i * NBLK + b] = hd[i];
        cnt_mat[MATP + i * NBLK + b] = hs[i];
    }
}

// ---------------- flat exclusive scan (3-phase) ----------------
__global__ __launch_bounds__(1024) void scan_blocks(const int* __restrict__ counts,
                                                    int* __restrict__ out,
                                                    int* __restrict__ partials, int n) {
    __shared__ int tmp[1024];
    int i = blockIdx.x * 1024 + threadIdx.x;
    int v = (i < n) ? counts[i] : 0;
    tmp[threadIdx.x] = v;
    __syncthreads();
    for (int off = 1; off < 1024; off <<= 1) {
        int t = (threadIdx.x >= (unsigned)off) ? tmp[threadIdx.x - off] : 0;
        __syncthreads();
        tmp[threadIdx.x] += t;
        __syncthreads();
    }
    if (i < n) out[i] = tmp[threadIdx.x] - v;  // exclusive
    if (threadIdx.x == 1023) partials[blockIdx.x] = tmp[1023];
}

__global__ void scan_partials(int* __restrict__ partials, int nb) {
    if (threadIdx.x == 0 && blockIdx.x == 0) {
        int s = 0;
        for (int b = 0; b < nb; ++b) { int t = partials[b]; partials[b] = s; s += t; }
    }
}

__global__ void scan_add(int* __restrict__ data, const int* __restrict__ partials, int n) {
    int i = blockIdx.x * blockDim.x + threadIdx.x;
    if (i < n) data[i] += partials[i >> 10];
}

// ---------------- phase 2: scatter edges into bucket-sorted streams ------
// tmp[0..E): dst-bucketed, packed (dst&255)<<17 | src
// tmp[E..2E): src-bucketed, value = src
__global__ __launch_bounds__(256) void bucket_scatter(const int* __restrict__ esrc,
                                                      const int* __restrict__ edst,
                                                      const int* __restrict__ scan_mat,
                                                      unsigned int* __restrict__ tmp) {
    __shared__ int cd[NBUCK], cs[NBUCK];
    const int b = blockIdx.x, t = threadIdx.x;
    for (int i = t; i < NBUCK; i += 256) {
        cd[i] = scan_mat[i * NBLK + b];
        cs[i] = scan_mat[MATP + i * NBLK + b];
    }
    __syncthreads();
    const int e1 = (b + 1) * CHUNK;
    for (int e = b * CHUNK + t; e < e1; e += 256) {
        int s = esrc[e], d = edst[e];
        int pd = atomicAdd(&cd[d >> 8], 1);
        tmp[pd] = ((unsigned int)(d & 255) << 17) | (unsigned int)s;
        int ps = atomicAdd(&cs[s >> 8], 1);
        tmp[ps] = (unsigned int)s;
    }
}

// ---------------- phase 3a: per-bucket fine sort -> rowptr, csr_src, ndst -
__global__ __launch_bounds__(256) void finalize_dst(const unsigned int* __restrict__ tmp,
                                                    const int* __restrict__ scan_mat,
                                                    int* __restrict__ rowptr,
                                                    int* __restrict__ csr_src,
                                                    float* __restrict__ ndst) {
    __shared__ int hist[256];
    __shared__ int scn[256];
    __shared__ int cur[256];
    const int b = blockIdx.x, t = threadIdx.x;
    const int beg = scan_mat[b * 256];
    const int end = scan_mat[(b + 1) * 256];   // b=NBUCK-1 -> scan_mat[MATP] == E
    hist[t] = 0;
    __syncthreads();
    for (int j = beg + t; j < end; j += 256)
        atomicAdd(&hist[tmp[j] >> 17], 1);
    __syncthreads();
    int v = hist[t];
    scn[t] = v;
    __syncthreads();
    for (int off = 1; off < 256; off <<= 1) {
        int u = (t >= off) ? scn[t - off] : 0;
        __syncthreads();
        scn[t] += u;
        __syncthreads();
    }
    int excl = scn[t] - v;
    int node = b * 256 + t;
    if (node <= N_NODES) rowptr[node] = beg + excl;
    if (node < N_NODES) ndst[node] = rsqrtf(fmaxf((float)v, 1.0f));
    cur[t] = beg + excl;
    __syncthreads();
    for (int j = beg + t; j < end; j += 256) {
        unsigned int x = tmp[j];
        int pos = atomicAdd(&cur[x >> 17], 1);
        csr_src[pos] = (int)(x & 0x1FFFFu);
    }
}

// ---------------- phase 3b: per-bucket src histogram -> nsrc -------------
__global__ __launch_bounds__(256) void finalize_src(const unsigned int* __restrict__ tmp,
                                                    const int* __restrict__ scan_mat,
                                                    float* __restrict__ nsrc) {
    __shared__ int hist[256];
    const int b = blockIdx.x, t = threadIdx.x;
    const int beg = scan_mat[MATP + b * 256];
    const int end = (b < NBUCK - 1) ? scan_mat[MATP + (b + 1) * 256] : 2 * N_EDGES;
    hist[t] = 0;
    __syncthreads();
    for (int j = beg + t; j < end; j += 256)
        atomicAdd(&hist[tmp[j] & 255u], 1);
    __syncthreads();
    int node = b * 256 + t;
    if (node < N_NODES) nsrc[node] = rsqrtf(fmaxf((float)hist[t], 1.0f));
}

// ---------------- W -> W^T split into bf16 hi/lo ----------------
template<int K>
__global__ void wtsplit_kernel(const float* __restrict__ W,
                               unsigned short* __restrict__ WTh,
                               unsigned short* __restrict__ WTl) {
    int i = blockIdx.x * blockDim.x + threadIdx.x;
    if (i < 128 * K) {
        int col = i / K, k = i % K;
        float x = W[(size_t)k * 128 + col];
        unsigned short h = f32_to_bf16_rne(x);
        unsigned short l = f32_to_bf16_rne(x - bf16_bits_to_f32(h));
        WTh[i] = h;
        WTl[i] = l;
    }
}

// ---------------- MFMA GEMM (bf16 3-term split) with fused row scaling ----
template<int K>
__global__ __launch_bounds__(256) void gemm_mfma(
    const float* __restrict__ A,            // [M, K] f32
    const unsigned short* __restrict__ WTh, // [128][K] bf16 hi
    const unsigned short* __restrict__ WTl, // [128][K] bf16 lo
    const float* __restrict__ rowscale,     // [M]
    float* __restrict__ C,                  // [M, 128]
    int M)
{
    __shared__ unsigned short Ah[128 * 64];
    __shared__ unsigned short Al[128 * 64];
    __shared__ unsigned short Bh[128 * 64];
    __shared__ unsigned short Bl[128 * 64];

    const int tid = threadIdx.x;
    const int bm = blockIdx.x * 128;
    const int lane = tid & 63;
    const int wid = tid >> 6;
    const int wm = wid >> 1;
    const int wn = wid & 1;
    const int lr = lane & 15;
    const int lg = lane >> 4;

    f32x4 acc[4][4];
    #pragma unroll
    for (int i = 0; i < 4; ++i)
        #pragma unroll
        for (int j = 0; j < 4; ++j)
            acc[i][j] = (f32x4){0.f, 0.f, 0.f, 0.f};

    for (int k0 = 0; k0 < K; k0 += 64) {
        #pragma unroll
        for (int i = 0; i < 4; ++i) {
            int lin = tid + i * 256;
            int row = lin >> 3;
            int s8  = lin & 7;
            int rg  = bm + row;
            float v[8];
            if (rg < M) {
                const float* ap = &A[(size_t)rg * K + k0 + s8 * 8];
                float4 v0 = *reinterpret_cast<const float4*>(ap);
                float4 v1 = *reinterpret_cast<const float4*>(ap + 4);
                v[0] = v0.x; v[1] = v0.y; v[2] = v0.z; v[3] = v0.w;
                v[4] = v1.x; v[5] = v1.y; v[6] = v1.z; v[7] = v1.w;
            } else {
                #pragma unroll
                for (int j = 0; j < 8; ++j) v[j] = 0.f;
            }
            u16x8 vh, vl;
            #pragma unroll
            for (int j = 0; j < 8; ++j) {
                unsigned short h = f32_to_bf16_rne(v[j]);
                vh[j] = h;
                vl[j] = f32_to_bf16_rne(v[j] - bf16_bits_to_f32(h));
            }
            int off = row * 64 + ((s8 ^ (row & 7)) << 3);
            *reinterpret_cast<u16x8*>(&Ah[off]) = vh;
            *reinterpret_cast<u16x8*>(&Al[off]) = vl;
        }
        #pragma unroll
        for (int i = 0; i < 4; ++i) {
            int lin = tid + i * 256;
            int col = lin >> 3;
            int s8  = lin & 7;
            const size_t g = (size_t)col * K + k0 + s8 * 8;
            u16x8 vh = *reinterpret_cast<const u16x8*>(&WTh[g]);
            u16x8 vl = *reinterpret_cast<const u16x8*>(&WTl[g]);
            int off = col * 64 + ((s8 ^ (col & 7)) << 3);
            *reinterpret_cast<u16x8*>(&Bh[off]) = vh;
            *reinterpret_cast<u16x8*>(&Bl[off]) = vl;
        }
        __syncthreads();

        #pragma unroll
        for (int ks = 0; ks < 2; ++ks) {
            const int s8 = ks * 4 + lg;
            bf16x8 afh[4], afl[4], bfh[4], bfl[4];
            #pragma unroll
            for (int mt = 0; mt < 4; ++mt) {
                int row = wm * 64 + mt * 16 + lr;
                int off = row * 64 + ((s8 ^ (row & 7)) << 3);
                afh[mt] = *reinterpret_cast<const bf16x8*>(&Ah[off]);
                afl[mt] = *reinterpret_cast<const bf16x8*>(&Al[off]);
            }
            #pragma unroll
            for (int nt = 0; nt < 4; ++nt) {
                int col = wn * 64 + nt * 16 + lr;
                int off = col * 64 + ((s8 ^ (col & 7)) << 3);
                bfh[nt] = *reinterpret_cast<const bf16x8*>(&Bh[off]);
                bfl[nt] = *reinterpret_cast<const bf16x8*>(&Bl[off]);
            }
            #pragma unroll
            for (int mt = 0; mt < 4; ++mt) {
                #pragma unroll
                for (int nt = 0; nt < 4; ++nt) {
                    acc[mt][nt] = __builtin_amdgcn_mfma_f32_16x16x32_bf16(
                        afh[mt], bfh[nt], acc[mt][nt], 0, 0, 0);
                    acc[mt][nt] = __builtin_amdgcn_mfma_f32_16x16x32_bf16(
                        afh[mt], bfl[nt], acc[mt][nt], 0, 0, 0);
                    acc[mt][nt] = __builtin_amdgcn_mfma_f32_16x16x32_bf16(
                        afl[mt], bfh[nt], acc[mt][nt], 0, 0, 0);
                }
            }
        }
        __syncthreads();
    }

    #pragma unroll
    for (int mt = 0; mt < 4; ++mt) {
        #pragma unroll
        for (int r = 0; r < 4; ++r) {
            int row = bm + wm * 64 + mt * 16 + lg * 4 + r;
            if (row < M) {
                float s = rowscale[row];
                #pragma unroll
                for (int nt = 0; nt < 4; ++nt) {
                    int col = wn * 64 + nt * 16 + lr;
                    C[(size_t)row * 128 + col] = acc[mt][nt][r] * s;
                }
            }
        }
    }
}

// ---------------- CSR aggregation, fused epilogue ----------------
__global__ void aggregate_kernel(const float* __restrict__ h,
                                 const int* __restrict__ rowptr,
                                 const int* __restrict__ csr_src,
                                 const float* __restrict__ ndst,
                                 const float* __restrict__ bias,
                                 float* __restrict__ out, int N) {
    long long tid = (long long)blockIdx.x * blockDim.x + threadIdx.x;
    int node = (int)(tid >> 5);
    if (node >= N) return;
    int c = ((int)tid & 31) * 4;
    int beg = rowptr[node];
    int end = rowptr[node + 1];
    float4 acc = make_float4(0.f, 0.f, 0.f, 0.f);
    for (int j = beg; j < end; ++j) {
        int s = csr_src[j];
        float4 v = *reinterpret_cast<const float4*>(&h[(size_t)s * 128 + c]);
        acc.x += v.x; acc.y += v.y; acc.z += v.z; acc.w += v.w;
    }
    float sc = ndst[node];
    float4 b = *reinterpret_cast<const float4*>(&bias[c]);
    float4 r;
    r.x = fmaxf(acc.x * sc + b.x, 0.f);
    r.y = fmaxf(acc.y * sc + b.y, 0.f);
    r.z = fmaxf(acc.z * sc + b.z, 0.f);
    r.w = fmaxf(acc.w * sc + b.w, 0.f);
    *reinterpret_cast<float4*>(&out[(size_t)node * 128 + c]) = r;
}

extern "C" void kernel_launch(void* const* d_in, const int* in_sizes, int n_in,
                              void* d_out, int out_size, void* d_ws, size_t ws_size,
                              hipStream_t stream) {
    const float* feat = (const float*)d_in[0];   // [1, N, 256]
    const float* W1   = (const float*)d_in[1];   // [256, 128]
    const float* b1   = (const float*)d_in[2];   // [128]
    const float* W2   = (const float*)d_in[3];   // [128, 128]
    const float* b2   = (const float*)d_in[4];   // [128]
    const int* esrc   = (const int*)d_in[5];     // [E]
    const int* edst   = (const int*)d_in[6];     // [E]
    float* out = (float*)d_out;                  // [N, 128]

    const int Nn = N_NODES, E = N_EDGES;
    const int SCAN_N = 2 * MATP;                 // 200192
    const int SCAN_NB = (SCAN_N + 1023) / 1024;  // 196

    // workspace layout (16B-aligned segments):
    // h[N*128] f32 | WT1h/WT1l[128*256] u16 | WT2h/WT2l[128*128] u16 |
    // csr_src[E] | rowptr[100004] | tmp[2E] u32 | cnt_mat[SCAN_N] | scan_mat[SCAN_N] | partials
    float* h      = (float*)d_ws;
    unsigned short* WT1h = (unsigned short*)(h + (size_t)Nn * 128);
    unsigned short* WT1l = WT1h + 128 * 256;
    unsigned short* WT2h = WT1l + 128 * 256;
    unsigned short* WT2l = WT2h + 128 * 128;
    int* csr_src  = (int*)(WT2l + 128 * 128);
    int* rowptr   = csr_src + E;
    unsigned int* tmp = (unsigned int*)(rowptr + 100004);
    int* cnt_mat  = (int*)(tmp + 2 * (size_t)E);
    int* scan_mat = cnt_mat + SCAN_N;
    int* partials = scan_mat + SCAN_N;
    float* nsrc   = (float*)(partials + ((SCAN_NB + 3) & ~3));
    float* ndst   = nsrc + Nn;

    // --- weight transpose+split (tiny) ---
    wtsplit_kernel<256><<<(128 * 256 + 255) / 256, 256, 0, stream>>>(W1, WT1h, WT1l);
    wtsplit_kernel<128><<<(128 * 128 + 255) / 256, 256, 0, stream>>>(W2, WT2h, WT2l);

    // --- CSR + degrees via bucket sort (LDS atomics only) ---
    bucket_count<<<NBLK, 256, 0, stream>>>(esrc, edst, cnt_mat);
    scan_blocks<<<SCAN_NB, 1024, 0, stream>>>(cnt_mat, scan_mat, partials, SCAN_N);
    scan_partials<<<1, 64, 0, stream>>>(partials, SCAN_NB);
    scan_add<<<(SCAN_N + 255) / 256, 256, 0, stream>>>(scan_mat, partials, SCAN_N);
    bucket_scatter<<<NBLK, 256, 0, stream>>>(esrc, edst, scan_mat, tmp);
    finalize_dst<<<NBUCK, 256, 0, stream>>>(tmp, scan_mat, rowptr, csr_src, ndst);
    finalize_src<<<NBUCK, 256, 0, stream>>>(tmp, scan_mat, nsrc);

    // --- layer 1: gemm -> h; aggregate -> d_out ---
    gemm_mfma<256><<<(Nn + 127) / 128, 256, 0, stream>>>(feat, WT1h, WT1l, nsrc, h, Nn);
    aggregate_kernel<<<(int)(((long long)Nn * 32 + 255) / 256), 256, 0, stream>>>(
        h, rowptr, csr_src, ndst, b1, out, Nn);

    // --- layer 2: gemm (reads d_out) -> h; aggregate -> d_out ---
    gemm_mfma<128><<<(Nn + 127) / 128, 256, 0, stream>>>(out, WT2h, WT2l, nsrc, h, Nn);
    aggregate_kernel<<<(int)(((long long)Nn * 32 + 255) / 256), 256, 0, stream>>>(
        h, rowptr, csr_src, ndst, b2, out, Nn);
}

// Round 5
// 297.815 us; speedup vs baseline: 19.5119x; 1.3912x over previous
//
#include <hip/hip_runtime.h>
#include <hip/hip_bf16.h>

#define N_NODES 100000
#define N_EDGES 1600000
#define NBUCK 391          // ceil(N_NODES / 256)
#define NBLK 256           // bucket-phase blocks
#define CHUNK (N_EDGES / NBLK)   // 6250, exact
#define MATP (NBUCK * NBLK)      // 100096, per-part count-matrix size

typedef __bf16 bf16x8 __attribute__((ext_vector_type(8)));
typedef float f32x4 __attribute__((ext_vector_type(4)));
typedef unsigned short u16x8 __attribute__((ext_vector_type(8)));
typedef _Float16 f16x8 __attribute__((ext_vector_type(8)));

// ---------------- helpers: f32 -> bf16 (RNE) split ----------------
__device__ __forceinline__ unsigned short f32_to_bf16_rne(float x) {
    unsigned int u = __float_as_uint(x);
    unsigned int r = u + 0x7FFFu + ((u >> 16) & 1u);
    return (unsigned short)(r >> 16);
}
__device__ __forceinline__ float bf16_bits_to_f32(unsigned short h) {
    return __uint_as_float(((unsigned int)h) << 16);
}

// ---------------- phase 1: coarse bucket histograms (LDS atomics only) ----
__global__ __launch_bounds__(256) void bucket_count(const int* __restrict__ esrc,
                                                    const int* __restrict__ edst,
                                                    int* __restrict__ cnt_mat) {
    __shared__ int hd[NBUCK], hs[NBUCK];
    const int b = blockIdx.x, t = threadIdx.x;
    for (int i = t; i < NBUCK; i += 256) { hd[i] = 0; hs[i] = 0; }
    __syncthreads();
    const int e1 = (b + 1) * CHUNK;
    for (int e = b * CHUNK + t; e < e1; e += 256) {
        atomicAdd(&hd[edst[e] >> 8], 1);
        atomicAdd(&hs[esrc[e] >> 8], 1);
    }
    __syncthreads();
    for (int i = t; i < NBUCK; i += 256) {
        cnt_mat[i * NBLK + b] = hd[i];
        cnt_mat[MATP + i * NBLK + b] = hs[i];
    }
}

// ---------------- flat exclusive scan (3-phase) ----------------
__global__ __launch_bounds__(1024) void scan_blocks(const int* __restrict__ counts,
                                                    int* __restrict__ out,
                                                    int* __restrict__ partials, int n) {
    __shared__ int tmp[1024];
    int i = blockIdx.x * 1024 + threadIdx.x;
    int v = (i < n) ? counts[i] : 0;
    tmp[threadIdx.x] = v;
    __syncthreads();
    for (int off = 1; off < 1024; off <<= 1) {
        int t = (threadIdx.x >= (unsigned)off) ? tmp[threadIdx.x - off] : 0;
        __syncthreads();
        tmp[threadIdx.x] += t;
        __syncthreads();
    }
    if (i < n) out[i] = tmp[threadIdx.x] - v;  // exclusive
    if (threadIdx.x == 1023) partials[blockIdx.x] = tmp[1023];
}

__global__ void scan_partials(int* __restrict__ partials, int nb) {
    if (threadIdx.x == 0 && blockIdx.x == 0) {
        int s = 0;
        for (int b = 0; b < nb; ++b) { int t = partials[b]; partials[b] = s; s += t; }
    }
}

__global__ void scan_add(int* __restrict__ data, const int* __restrict__ partials, int n) {
    int i = blockIdx.x * blockDim.x + threadIdx.x;
    if (i < n) data[i] += partials[i >> 10];
}

// ---------------- phase 2: scatter edges into bucket-sorted streams ------
__global__ __launch_bounds__(256) void bucket_scatter(const int* __restrict__ esrc,
                                                      const int* __restrict__ edst,
                                                      const int* __restrict__ scan_mat,
                                                      unsigned int* __restrict__ tmp) {
    __shared__ int cd[NBUCK], cs[NBUCK];
    const int b = blockIdx.x, t = threadIdx.x;
    for (int i = t; i < NBUCK; i += 256) {
        cd[i] = scan_mat[i * NBLK + b];
        cs[i] = scan_mat[MATP + i * NBLK + b];
    }
    __syncthreads();
    const int e1 = (b + 1) * CHUNK;
    for (int e = b * CHUNK + t; e < e1; e += 256) {
        int s = esrc[e], d = edst[e];
        int pd = atomicAdd(&cd[d >> 8], 1);
        tmp[pd] = ((unsigned int)(d & 255) << 17) | (unsigned int)s;
        int ps = atomicAdd(&cs[s >> 8], 1);
        tmp[ps] = (unsigned int)s;
    }
}

// ---------------- phase 3a: per-bucket fine sort -> rowptr, csr_src, ndst -
__global__ __launch_bounds__(256) void finalize_dst(const unsigned int* __restrict__ tmp,
                                                    const int* __restrict__ scan_mat,
                                                    int* __restrict__ rowptr,
                                                    int* __restrict__ csr_src,
                                                    float* __restrict__ ndst) {
    __shared__ int hist[256];
    __shared__ int scn[256];
    __shared__ int cur[256];
    const int b = blockIdx.x, t = threadIdx.x;
    const int beg = scan_mat[b * 256];
    const int end = scan_mat[(b + 1) * 256];
    hist[t] = 0;
    __syncthreads();
    for (int j = beg + t; j < end; j += 256)
        atomicAdd(&hist[tmp[j] >> 17], 1);
    __syncthreads();
    int v = hist[t];
    scn[t] = v;
    __syncthreads();
    for (int off = 1; off < 256; off <<= 1) {
        int u = (t >= off) ? scn[t - off] : 0;
        __syncthreads();
        scn[t] += u;
        __syncthreads();
    }
    int excl = scn[t] - v;
    int node = b * 256 + t;
    if (node <= N_NODES) rowptr[node] = beg + excl;
    if (node < N_NODES) ndst[node] = rsqrtf(fmaxf((float)v, 1.0f));
    cur[t] = beg + excl;
    __syncthreads();
    for (int j = beg + t; j < end; j += 256) {
        unsigned int x = tmp[j];
        int pos = atomicAdd(&cur[x >> 17], 1);
        csr_src[pos] = (int)(x & 0x1FFFFu);
    }
}

// ---------------- phase 3b: per-bucket src histogram -> nsrc -------------
__global__ __launch_bounds__(256) void finalize_src(const unsigned int* __restrict__ tmp,
                                                    const int* __restrict__ scan_mat,
                                                    float* __restrict__ nsrc) {
    __shared__ int hist[256];
    const int b = blockIdx.x, t = threadIdx.x;
    const int beg = scan_mat[MATP + b * 256];
    const int end = (b < NBUCK - 1) ? scan_mat[MATP + (b + 1) * 256] : 2 * N_EDGES;
    hist[t] = 0;
    __syncthreads();
    for (int j = beg + t; j < end; j += 256)
        atomicAdd(&hist[tmp[j] & 255u], 1);
    __syncthreads();
    int node = b * 256 + t;
    if (node < N_NODES) nsrc[node] = rsqrtf(fmaxf((float)hist[t], 1.0f));
}

// ---------------- W -> W^T split into bf16 hi/lo ----------------
template<int K>
__global__ void wtsplit_kernel(const float* __restrict__ W,
                               unsigned short* __restrict__ WTh,
                               unsigned short* __restrict__ WTl) {
    int i = blockIdx.x * blockDim.x + threadIdx.x;
    if (i < 128 * K) {
        int col = i / K, k = i % K;
        float x = W[(size_t)k * 128 + col];
        unsigned short h = f32_to_bf16_rne(x);
        unsigned short l = f32_to_bf16_rne(x - bf16_bits_to_f32(h));
        WTh[i] = h;
        WTl[i] = l;
    }
}

// ---------------- MFMA GEMM (bf16 3-term split), f16 output --------------
// C16[m, 0:128] = (f16) rowscale[m] * sum_k A[m,k] * W[k, 0:128]
template<int K>
__global__ __launch_bounds__(256) void gemm_mfma(
    const float* __restrict__ A,            // [M, K] f32
    const unsigned short* __restrict__ WTh, // [128][K] bf16 hi
    const unsigned short* __restrict__ WTl, // [128][K] bf16 lo
    const float* __restrict__ rowscale,     // [M]
    _Float16* __restrict__ C16,             // [M, 128] f16 out
    int M)
{
    __shared__ unsigned short Ah[128 * 64];
    __shared__ unsigned short Al[128 * 64];
    __shared__ unsigned short Bh[128 * 64];
    __shared__ unsigned short Bl[128 * 64];

    const int tid = threadIdx.x;
    const int bm = blockIdx.x * 128;
    const int lane = tid & 63;
    const int wid = tid >> 6;
    const int wm = wid >> 1;
    const int wn = wid & 1;
    const int lr = lane & 15;
    const int lg = lane >> 4;

    f32x4 acc[4][4];
    #pragma unroll
    for (int i = 0; i < 4; ++i)
        #pragma unroll
        for (int j = 0; j < 4; ++j)
            acc[i][j] = (f32x4){0.f, 0.f, 0.f, 0.f};

    for (int k0 = 0; k0 < K; k0 += 64) {
        #pragma unroll
        for (int i = 0; i < 4; ++i) {
            int lin = tid + i * 256;
            int row = lin >> 3;
            int s8  = lin & 7;
            int rg  = bm + row;
            float v[8];
            if (rg < M) {
                const float* ap = &A[(size_t)rg * K + k0 + s8 * 8];
                float4 v0 = *reinterpret_cast<const float4*>(ap);
                float4 v1 = *reinterpret_cast<const float4*>(ap + 4);
                v[0] = v0.x; v[1] = v0.y; v[2] = v0.z; v[3] = v0.w;
                v[4] = v1.x; v[5] = v1.y; v[6] = v1.z; v[7] = v1.w;
            } else {
                #pragma unroll
                for (int j = 0; j < 8; ++j) v[j] = 0.f;
            }
            u16x8 vh, vl;
            #pragma unroll
            for (int j = 0; j < 8; ++j) {
                unsigned short h = f32_to_bf16_rne(v[j]);
                vh[j] = h;
                vl[j] = f32_to_bf16_rne(v[j] - bf16_bits_to_f32(h));
            }
            int off = row * 64 + ((s8 ^ (row & 7)) << 3);
            *reinterpret_cast<u16x8*>(&Ah[off]) = vh;
            *reinterpret_cast<u16x8*>(&Al[off]) = vl;
        }
        #pragma unroll
        for (int i = 0; i < 4; ++i) {
            int lin = tid + i * 256;
            int col = lin >> 3;
            int s8  = lin & 7;
            const size_t g = (size_t)col * K + k0 + s8 * 8;
            u16x8 vh = *reinterpret_cast<const u16x8*>(&WTh[g]);
            u16x8 vl = *reinterpret_cast<const u16x8*>(&WTl[g]);
            int off = col * 64 + ((s8 ^ (col & 7)) << 3);
            *reinterpret_cast<u16x8*>(&Bh[off]) = vh;
            *reinterpret_cast<u16x8*>(&Bl[off]) = vl;
        }
        __syncthreads();

        #pragma unroll
        for (int ks = 0; ks < 2; ++ks) {
            const int s8 = ks * 4 + lg;
            bf16x8 afh[4], afl[4], bfh[4], bfl[4];
            #pragma unroll
            for (int mt = 0; mt < 4; ++mt) {
                int row = wm * 64 + mt * 16 + lr;
                int off = row * 64 + ((s8 ^ (row & 7)) << 3);
                afh[mt] = *reinterpret_cast<const bf16x8*>(&Ah[off]);
                afl[mt] = *reinterpret_cast<const bf16x8*>(&Al[off]);
            }
            #pragma unroll
            for (int nt = 0; nt < 4; ++nt) {
                int col = wn * 64 + nt * 16 + lr;
                int off = col * 64 + ((s8 ^ (col & 7)) << 3);
                bfh[nt] = *reinterpret_cast<const bf16x8*>(&Bh[off]);
                bfl[nt] = *reinterpret_cast<const bf16x8*>(&Bl[off]);
            }
            #pragma unroll
            for (int mt = 0; mt < 4; ++mt) {
                #pragma unroll
                for (int nt = 0; nt < 4; ++nt) {
                    acc[mt][nt] = __builtin_amdgcn_mfma_f32_16x16x32_bf16(
                        afh[mt], bfh[nt], acc[mt][nt], 0, 0, 0);
                    acc[mt][nt] = __builtin_amdgcn_mfma_f32_16x16x32_bf16(
                        afh[mt], bfl[nt], acc[mt][nt], 0, 0, 0);
                    acc[mt][nt] = __builtin_amdgcn_mfma_f32_16x16x32_bf16(
                        afl[mt], bfh[nt], acc[mt][nt], 0, 0, 0);
                }
            }
        }
        __syncthreads();
    }

    #pragma unroll
    for (int mt = 0; mt < 4; ++mt) {
        #pragma unroll
        for (int r = 0; r < 4; ++r) {
            int row = bm + wm * 64 + mt * 16 + lg * 4 + r;
            if (row < M) {
                float s = rowscale[row];
                #pragma unroll
                for (int nt = 0; nt < 4; ++nt) {
                    int col = wn * 64 + nt * 16 + lr;
                    C16[(size_t)row * 128 + col] = (_Float16)(acc[mt][nt][r] * s);
                }
            }
        }
    }
}

// ---------------- CSR aggregation over f16 rows, fused epilogue ----------
// out[n,:] = relu( (sum_{e in in(n)} h16[csr_src[e],:]) * ndst[n] + bias )
// 16 lanes per node, 8 cols each (16B loads).
__global__ __launch_bounds__(256) void aggregate_kernel(
    const _Float16* __restrict__ h16,
    const int* __restrict__ rowptr,
    const int* __restrict__ csr_src,
    const float* __restrict__ ndst,
    const float* __restrict__ bias,
    float* __restrict__ out, int N)
{
    int g = blockIdx.x * blockDim.x + threadIdx.x;
    int node = g >> 4;
    if (node >= N) return;
    int c8 = (g & 15) * 8;
    int beg = rowptr[node];
    int end = rowptr[node + 1];
    float acc[8] = {0.f, 0.f, 0.f, 0.f, 0.f, 0.f, 0.f, 0.f};
    int j = beg;
    for (; j + 1 < end; j += 2) {
        int s0 = csr_src[j];
        int s1 = csr_src[j + 1];
        f16x8 v0 = *reinterpret_cast<const f16x8*>(&h16[(size_t)s0 * 128 + c8]);
        f16x8 v1 = *reinterpret_cast<const f16x8*>(&h16[(size_t)s1 * 128 + c8]);
        #pragma unroll
        for (int k = 0; k < 8; ++k) acc[k] += (float)v0[k] + (float)v1[k];
    }
    if (j < end) {
        int s0 = csr_src[j];
        f16x8 v0 = *reinterpret_cast<const f16x8*>(&h16[(size_t)s0 * 128 + c8]);
        #pragma unroll
        for (int k = 0; k < 8; ++k) acc[k] += (float)v0[k];
    }
    float sc = ndst[node];
    const float4 b0 = *reinterpret_cast<const float4*>(&bias[c8]);
    const float4 b1 = *reinterpret_cast<const float4*>(&bias[c8 + 4]);
    float4 r0, r1;
    r0.x = fmaxf(acc[0] * sc + b0.x, 0.f);
    r0.y = fmaxf(acc[1] * sc + b0.y, 0.f);
    r0.z = fmaxf(acc[2] * sc + b0.z, 0.f);
    r0.w = fmaxf(acc[3] * sc + b0.w, 0.f);
    r1.x = fmaxf(acc[4] * sc + b1.x, 0.f);
    r1.y = fmaxf(acc[5] * sc + b1.y, 0.f);
    r1.z = fmaxf(acc[6] * sc + b1.z, 0.f);
    r1.w = fmaxf(acc[7] * sc + b1.w, 0.f);
    float* op = &out[(size_t)node * 128 + c8];
    *reinterpret_cast<float4*>(op) = r0;
    *reinterpret_cast<float4*>(op + 4) = r1;
}

extern "C" void kernel_launch(void* const* d_in, const int* in_sizes, int n_in,
                              void* d_out, int out_size, void* d_ws, size_t ws_size,
                              hipStream_t stream) {
    const float* feat = (const float*)d_in[0];   // [1, N, 256]
    const float* W1   = (const float*)d_in[1];   // [256, 128]
    const float* b1   = (const float*)d_in[2];   // [128]
    const float* W2   = (const float*)d_in[3];   // [128, 128]
    const float* b2   = (const float*)d_in[4];   // [128]
    const int* esrc   = (const int*)d_in[5];     // [E]
    const int* edst   = (const int*)d_in[6];     // [E]
    float* out = (float*)d_out;                  // [N, 128]

    const int Nn = N_NODES, E = N_EDGES;
    const int SCAN_N = 2 * MATP;                 // 200192
    const int SCAN_NB = (SCAN_N + 1023) / 1024;  // 196

    // workspace layout (same segment sizes as before; h segment now holds f16)
    float* hseg   = (float*)d_ws;                              // [N*128] f32-sized slot
    _Float16* h16 = (_Float16*)hseg;                           // uses half the slot
    unsigned short* WT1h = (unsigned short*)(hseg + (size_t)Nn * 128);
    unsigned short* WT1l = WT1h + 128 * 256;
    unsigned short* WT2h = WT1l + 128 * 256;
    unsigned short* WT2l = WT2h + 128 * 128;
    int* csr_src  = (int*)(WT2l + 128 * 128);
    int* rowptr   = csr_src + E;
    unsigned int* tmp = (unsigned int*)(rowptr + 100004);
    int* cnt_mat  = (int*)(tmp + 2 * (size_t)E);
    int* scan_mat = cnt_mat + SCAN_N;
    int* partials = scan_mat + SCAN_N;
    float* nsrc   = (float*)(partials + ((SCAN_NB + 3) & ~3));
    float* ndst   = nsrc + Nn;

    // --- weight transpose+split (tiny) ---
    wtsplit_kernel<256><<<(128 * 256 + 255) / 256, 256, 0, stream>>>(W1, WT1h, WT1l);
    wtsplit_kernel<128><<<(128 * 128 + 255) / 256, 256, 0, stream>>>(W2, WT2h, WT2l);

    // --- CSR + degrees via bucket sort (LDS atomics only) ---
    bucket_count<<<NBLK, 256, 0, stream>>>(esrc, edst, cnt_mat);
    scan_blocks<<<SCAN_NB, 1024, 0, stream>>>(cnt_mat, scan_mat, partials, SCAN_N);
    scan_partials<<<1, 64, 0, stream>>>(partials, SCAN_NB);
    scan_add<<<(SCAN_N + 255) / 256, 256, 0, stream>>>(scan_mat, partials, SCAN_N);
    bucket_scatter<<<NBLK, 256, 0, stream>>>(esrc, edst, scan_mat, tmp);
    finalize_dst<<<NBUCK, 256, 0, stream>>>(tmp, scan_mat, rowptr, csr_src, ndst);
    finalize_src<<<NBUCK, 256, 0, stream>>>(tmp, scan_mat, nsrc);

    const int agg_grid = (Nn * 16 + 255) / 256;

    // --- layer 1: gemm -> h16; aggregate -> d_out (f32 temp) ---
    gemm_mfma<256><<<(Nn + 127) / 128, 256, 0, stream>>>(feat, WT1h, WT1l, nsrc, h16, Nn);
    aggregate_kernel<<<agg_grid, 256, 0, stream>>>(h16, rowptr, csr_src, ndst, b1, out, Nn);

    // --- layer 2: gemm (reads d_out) -> h16; aggregate -> d_out final ---
    gemm_mfma<128><<<(Nn + 127) / 128, 256, 0, stream>>>(out, WT2h, WT2l, nsrc, h16, Nn);
    aggregate_kernel<<<agg_grid, 256, 0, stream>>>(h16, rowptr, csr_src, ndst, b2, out, Nn);
}

// Round 6
// 289.660 us; speedup vs baseline: 20.0613x; 1.0282x over previous
//
#include <hip/hip_runtime.h>
#include <hip/hip_bf16.h>

#define N_NODES 100000
#define N_EDGES 1600000
#define NBUCK 391          // ceil(N_NODES / 256)
#define NBLK 256           // bucket-phase blocks
#define CHUNK (N_EDGES / NBLK)   // 6250, exact
#define MATP (NBUCK * NBLK)      // 100096, per-part count-matrix size

typedef __bf16 bf16x8 __attribute__((ext_vector_type(8)));
typedef float f32x4 __attribute__((ext_vector_type(4)));
typedef unsigned short u16x8 __attribute__((ext_vector_type(8)));
typedef _Float16 f16x8 __attribute__((ext_vector_type(8)));

// ---------------- helpers: f32 -> bf16 (RNE) split ----------------
__device__ __forceinline__ unsigned short f32_to_bf16_rne(float x) {
    unsigned int u = __float_as_uint(x);
    unsigned int r = u + 0x7FFFu + ((u >> 16) & 1u);
    return (unsigned short)(r >> 16);
}
__device__ __forceinline__ float bf16_bits_to_f32(unsigned short h) {
    return __uint_as_float(((unsigned int)h) << 16);
}

// ---------------- phase 1: coarse bucket histograms (LDS atomics only) ----
__global__ __launch_bounds__(256) void bucket_count(const int* __restrict__ esrc,
                                                    const int* __restrict__ edst,
                                                    int* __restrict__ cnt_mat) {
    __shared__ int hd[NBUCK], hs[NBUCK];
    const int b = blockIdx.x, t = threadIdx.x;
    for (int i = t; i < NBUCK; i += 256) { hd[i] = 0; hs[i] = 0; }
    __syncthreads();
    const int e1 = (b + 1) * CHUNK;
    for (int e = b * CHUNK + t; e < e1; e += 256) {
        atomicAdd(&hd[edst[e] >> 8], 1);
        atomicAdd(&hs[esrc[e] >> 8], 1);
    }
    __syncthreads();
    for (int i = t; i < NBUCK; i += 256) {
        cnt_mat[i * NBLK + b] = hd[i];
        cnt_mat[MATP + i * NBLK + b] = hs[i];
    }
}

// ---------------- flat exclusive scan (3-phase) ----------------
__global__ __launch_bounds__(1024) void scan_blocks(const int* __restrict__ counts,
                                                    int* __restrict__ out,
                                                    int* __restrict__ partials, int n) {
    __shared__ int tmp[1024];
    int i = blockIdx.x * 1024 + threadIdx.x;
    int v = (i < n) ? counts[i] : 0;
    tmp[threadIdx.x] = v;
    __syncthreads();
    for (int off = 1; off < 1024; off <<= 1) {
        int t = (threadIdx.x >= (unsigned)off) ? tmp[threadIdx.x - off] : 0;
        __syncthreads();
        tmp[threadIdx.x] += t;
        __syncthreads();
    }
    if (i < n) out[i] = tmp[threadIdx.x] - v;  // exclusive
    if (threadIdx.x == 1023) partials[blockIdx.x] = tmp[1023];
}

__global__ void scan_partials(int* __restrict__ partials, int nb) {
    if (threadIdx.x == 0 && blockIdx.x == 0) {
        int s = 0;
        for (int b = 0; b < nb; ++b) { int t = partials[b]; partials[b] = s; s += t; }
    }
}

__global__ void scan_add(int* __restrict__ data, const int* __restrict__ partials, int n) {
    int i = blockIdx.x * blockDim.x + threadIdx.x;
    if (i < n) data[i] += partials[i >> 10];
}

// ---------------- phase 2: scatter edges into bucket-sorted streams ------
__global__ __launch_bounds__(256) void bucket_scatter(const int* __restrict__ esrc,
                                                      const int* __restrict__ edst,
                                                      const int* __restrict__ scan_mat,
                                                      unsigned int* __restrict__ tmp) {
    __shared__ int cd[NBUCK], cs[NBUCK];
    const int b = blockIdx.x, t = threadIdx.x;
    for (int i = t; i < NBUCK; i += 256) {
        cd[i] = scan_mat[i * NBLK + b];
        cs[i] = scan_mat[MATP + i * NBLK + b];
    }
    __syncthreads();
    const int e1 = (b + 1) * CHUNK;
    for (int e = b * CHUNK + t; e < e1; e += 256) {
        int s = esrc[e], d = edst[e];
        int pd = atomicAdd(&cd[d >> 8], 1);
        tmp[pd] = ((unsigned int)(d & 255) << 17) | (unsigned int)s;
        int ps = atomicAdd(&cs[s >> 8], 1);
        tmp[ps] = (unsigned int)s;
    }
}

// ---------------- phase 3a: per-bucket fine sort -> rowptr, csr_src, ndst -
__global__ __launch_bounds__(256) void finalize_dst(const unsigned int* __restrict__ tmp,
                                                    const int* __restrict__ scan_mat,
                                                    int* __restrict__ rowptr,
                                                    int* __restrict__ csr_src,
                                                    float* __restrict__ ndst) {
    __shared__ int hist[256];
    __shared__ int scn[256];
    __shared__ int cur[256];
    const int b = blockIdx.x, t = threadIdx.x;
    const int beg = scan_mat[b * 256];
    const int end = scan_mat[(b + 1) * 256];
    hist[t] = 0;
    __syncthreads();
    for (int j = beg + t; j < end; j += 256)
        atomicAdd(&hist[tmp[j] >> 17], 1);
    __syncthreads();
    int v = hist[t];
    scn[t] = v;
    __syncthreads();
    for (int off = 1; off < 256; off <<= 1) {
        int u = (t >= off) ? scn[t - off] : 0;
        __syncthreads();
        scn[t] += u;
        __syncthreads();
    }
    int excl = scn[t] - v;
    int node = b * 256 + t;
    if (node <= N_NODES) rowptr[node] = beg + excl;
    if (node < N_NODES) ndst[node] = rsqrtf(fmaxf((float)v, 1.0f));
    cur[t] = beg + excl;
    __syncthreads();
    for (int j = beg + t; j < end; j += 256) {
        unsigned int x = tmp[j];
        int pos = atomicAdd(&cur[x >> 17], 1);
        csr_src[pos] = (int)(x & 0x1FFFFu);
    }
}

// ---------------- phase 3b: per-bucket src histogram -> nsrc -------------
__global__ __launch_bounds__(256) void finalize_src(const unsigned int* __restrict__ tmp,
                                                    const int* __restrict__ scan_mat,
                                                    float* __restrict__ nsrc) {
    __shared__ int hist[256];
    const int b = blockIdx.x, t = threadIdx.x;
    const int beg = scan_mat[MATP + b * 256];
    const int end = (b < NBUCK - 1) ? scan_mat[MATP + (b + 1) * 256] : 2 * N_EDGES;
    hist[t] = 0;
    __syncthreads();
    for (int j = beg + t; j < end; j += 256)
        atomicAdd(&hist[tmp[j] & 255u], 1);
    __syncthreads();
    int node = b * 256 + t;
    if (node < N_NODES) nsrc[node] = rsqrtf(fmaxf((float)hist[t], 1.0f));
}

// ---------------- W -> W^T split into bf16 hi/lo ----------------
template<int K>
__global__ void wtsplit_kernel(const float* __restrict__ W,
                               unsigned short* __restrict__ WTh,
                               unsigned short* __restrict__ WTl) {
    int i = blockIdx.x * blockDim.x + threadIdx.x;
    if (i < 128 * K) {
        int col = i / K, k = i % K;
        float x = W[(size_t)k * 128 + col];
        unsigned short h = f32_to_bf16_rne(x);
        unsigned short l = f32_to_bf16_rne(x - bf16_bits_to_f32(h));
        WTh[i] = h;
        WTl[i] = l;
    }
}

// ---------------- MFMA GEMM (bf16 3-term split), f16 output --------------
// BM=64, BN=128, BK=32; 4 waves (2x2); LDS rows padded to 40 ushorts (80 B)
// -> conflict-free ds_read_b128 / staging writes; register prefetch pipeline.
template<int K>
__global__ __launch_bounds__(256) void gemm_mfma(
    const float* __restrict__ A,            // [M, K] f32
    const unsigned short* __restrict__ WTh, // [128][K] bf16 hi
    const unsigned short* __restrict__ WTl, // [128][K] bf16 lo
    const float* __restrict__ rowscale,     // [M]
    _Float16* __restrict__ C16,             // [M, 128] f16 out
    int M)
{
    constexpr int LDA = 40;  // padded row stride in ushorts (80 B)
    __shared__ unsigned short Ah[64 * LDA];
    __shared__ unsigned short Al[64 * LDA];
    __shared__ unsigned short Bh[128 * LDA];
    __shared__ unsigned short Bl[128 * LDA];

    const int tid = threadIdx.x;
    const int bm = blockIdx.x * 64;
    const int lane = tid & 63;
    const int wid = tid >> 6;
    const int wm = wid >> 1;         // 0..1: 32-row half
    const int wn = wid & 1;          // 0..1: 64-col half
    const int lr = lane & 15;
    const int lg = lane >> 4;

    // staging coords: A: row=tid>>2 (0..63), s8=tid&3; B: col=(tid+i*256)>>2, s8
    const int st_ar = tid >> 2;
    const int st_s8 = tid & 3;
    const int a_row_g = bm + st_ar;

    f32x4 acc[2][4];
    #pragma unroll
    for (int i = 0; i < 2; ++i)
        #pragma unroll
        for (int j = 0; j < 4; ++j)
            acc[i][j] = (f32x4){0.f, 0.f, 0.f, 0.f};

    // ---- prefetch registers ----
    float4 av0, av1;
    u16x8 bvh[2], bvl[2];

    auto load_tile = [&](int k0) {
        if (a_row_g < M) {
            const float* ap = &A[(size_t)a_row_g * K + k0 + st_s8 * 8];
            av0 = *reinterpret_cast<const float4*>(ap);
            av1 = *reinterpret_cast<const float4*>(ap + 4);
        } else {
            av0 = make_float4(0.f, 0.f, 0.f, 0.f);
            av1 = make_float4(0.f, 0.f, 0.f, 0.f);
        }
        #pragma unroll
        for (int i = 0; i < 2; ++i) {
            int lin = tid + i * 256;
            int col = lin >> 2;
            int s8  = lin & 3;
            const size_t g = (size_t)col * K + k0 + s8 * 8;
            bvh[i] = *reinterpret_cast<const u16x8*>(&WTh[g]);
            bvl[i] = *reinterpret_cast<const u16x8*>(&WTl[g]);
        }
    };

    load_tile(0);

    for (int k0 = 0; k0 < K; k0 += 32) {
        // ---- convert + write LDS from regs ----
        {
            float v[8] = {av0.x, av0.y, av0.z, av0.w, av1.x, av1.y, av1.z, av1.w};
            u16x8 vh, vl;
            #pragma unroll
            for (int j = 0; j < 8; ++j) {
                unsigned short h = f32_to_bf16_rne(v[j]);
                vh[j] = h;
                vl[j] = f32_to_bf16_rne(v[j] - bf16_bits_to_f32(h));
            }
            int off = st_ar * LDA + st_s8 * 8;
            *reinterpret_cast<u16x8*>(&Ah[off]) = vh;
            *reinterpret_cast<u16x8*>(&Al[off]) = vl;
            #pragma unroll
            for (int i = 0; i < 2; ++i) {
                int lin = tid + i * 256;
                int col = lin >> 2;
                int s8  = lin & 3;
                int boff = col * LDA + s8 * 8;
                *reinterpret_cast<u16x8*>(&Bh[boff]) = bvh[i];
                *reinterpret_cast<u16x8*>(&Bl[boff]) = bvl[i];
            }
        }
        __syncthreads();

        // ---- prefetch next tile while MFMA runs ----
        if (k0 + 32 < K) load_tile(k0 + 32);

        // ---- MFMA: one K=32 substep ----
        {
            bf16x8 afh[2], afl[2], bfh[4], bfl[4];
            #pragma unroll
            for (int mt = 0; mt < 2; ++mt) {
                int row = wm * 32 + mt * 16 + lr;
                int off = row * LDA + lg * 8;
                afh[mt] = *reinterpret_cast<const bf16x8*>(&Ah[off]);
                afl[mt] = *reinterpret_cast<const bf16x8*>(&Al[off]);
            }
            #pragma unroll
            for (int nt = 0; nt < 4; ++nt) {
                int col = wn * 64 + nt * 16 + lr;
                int off = col * LDA + lg * 8;
                bfh[nt] = *reinterpret_cast<const bf16x8*>(&Bh[off]);
                bfl[nt] = *reinterpret_cast<const bf16x8*>(&Bl[off]);
            }
            #pragma unroll
            for (int mt = 0; mt < 2; ++mt) {
                #pragma unroll
                for (int nt = 0; nt < 4; ++nt) {
                    acc[mt][nt] = __builtin_amdgcn_mfma_f32_16x16x32_bf16(
                        afh[mt], bfh[nt], acc[mt][nt], 0, 0, 0);
                    acc[mt][nt] = __builtin_amdgcn_mfma_f32_16x16x32_bf16(
                        afh[mt], bfl[nt], acc[mt][nt], 0, 0, 0);
                    acc[mt][nt] = __builtin_amdgcn_mfma_f32_16x16x32_bf16(
                        afl[mt], bfh[nt], acc[mt][nt], 0, 0, 0);
                }
            }
        }
        __syncthreads();
    }

    // ---- epilogue: scale rows, store f16 ----
    #pragma unroll
    for (int mt = 0; mt < 2; ++mt) {
        #pragma unroll
        for (int r = 0; r < 4; ++r) {
            int row = bm + wm * 32 + mt * 16 + lg * 4 + r;
            if (row < M) {
                float s = rowscale[row];
                #pragma unroll
                for (int nt = 0; nt < 4; ++nt) {
                    int col = wn * 64 + nt * 16 + lr;
                    C16[(size_t)row * 128 + col] = (_Float16)(acc[mt][nt][r] * s);
                }
            }
        }
    }
}

// ---------------- CSR aggregation over f16 rows, fused epilogue ----------
__global__ __launch_bounds__(256) void aggregate_kernel(
    const _Float16* __restrict__ h16,
    const int* __restrict__ rowptr,
    const int* __restrict__ csr_src,
    const float* __restrict__ ndst,
    const float* __restrict__ bias,
    float* __restrict__ out, int N)
{
    int g = blockIdx.x * blockDim.x + threadIdx.x;
    int node = g >> 4;
    if (node >= N) return;
    int c8 = (g & 15) * 8;
    int beg = rowptr[node];
    int end = rowptr[node + 1];
    float acc[8] = {0.f, 0.f, 0.f, 0.f, 0.f, 0.f, 0.f, 0.f};
    int j = beg;
    for (; j + 1 < end; j += 2) {
        int s0 = csr_src[j];
        int s1 = csr_src[j + 1];
        f16x8 v0 = *reinterpret_cast<const f16x8*>(&h16[(size_t)s0 * 128 + c8]);
        f16x8 v1 = *reinterpret_cast<const f16x8*>(&h16[(size_t)s1 * 128 + c8]);
        #pragma unroll
        for (int k = 0; k < 8; ++k) acc[k] += (float)v0[k] + (float)v1[k];
    }
    if (j < end) {
        int s0 = csr_src[j];
        f16x8 v0 = *reinterpret_cast<const f16x8*>(&h16[(size_t)s0 * 128 + c8]);
        #pragma unroll
        for (int k = 0; k < 8; ++k) acc[k] += (float)v0[k];
    }
    float sc = ndst[node];
    const float4 b0 = *reinterpret_cast<const float4*>(&bias[c8]);
    const float4 b1 = *reinterpret_cast<const float4*>(&bias[c8 + 4]);
    float4 r0, r1;
    r0.x = fmaxf(acc[0] * sc + b0.x, 0.f);
    r0.y = fmaxf(acc[1] * sc + b0.y, 0.f);
    r0.z = fmaxf(acc[2] * sc + b0.z, 0.f);
    r0.w = fmaxf(acc[3] * sc + b0.w, 0.f);
    r1.x = fmaxf(acc[4] * sc + b1.x, 0.f);
    r1.y = fmaxf(acc[5] * sc + b1.y, 0.f);
    r1.z = fmaxf(acc[6] * sc + b1.z, 0.f);
    r1.w = fmaxf(acc[7] * sc + b1.w, 0.f);
    float* op = &out[(size_t)node * 128 + c8];
    *reinterpret_cast<float4*>(op) = r0;
    *reinterpret_cast<float4*>(op + 4) = r1;
}

extern "C" void kernel_launch(void* const* d_in, const int* in_sizes, int n_in,
                              void* d_out, int out_size, void* d_ws, size_t ws_size,
                              hipStream_t stream) {
    const float* feat = (const float*)d_in[0];   // [1, N, 256]
    const float* W1   = (const float*)d_in[1];   // [256, 128]
    const float* b1   = (const float*)d_in[2];   // [128]
    const float* W2   = (const float*)d_in[3];   // [128, 128]
    const float* b2   = (const float*)d_in[4];   // [128]
    const int* esrc   = (const int*)d_in[5];     // [E]
    const int* edst   = (const int*)d_in[6];     // [E]
    float* out = (float*)d_out;                  // [N, 128]

    const int Nn = N_NODES, E = N_EDGES;
    const int SCAN_N = 2 * MATP;                 // 200192
    const int SCAN_NB = (SCAN_N + 1023) / 1024;  // 196

    // workspace layout (h segment holds f16 in an f32-sized slot)
    float* hseg   = (float*)d_ws;
    _Float16* h16 = (_Float16*)hseg;
    unsigned short* WT1h = (unsigned short*)(hseg + (size_t)Nn * 128);
    unsigned short* WT1l = WT1h + 128 * 256;
    unsigned short* WT2h = WT1l + 128 * 256;
    unsigned short* WT2l = WT2h + 128 * 128;
    int* csr_src  = (int*)(WT2l + 128 * 128);
    int* rowptr   = csr_src + E;
    unsigned int* tmp = (unsigned int*)(rowptr + 100004);
    int* cnt_mat  = (int*)(tmp + 2 * (size_t)E);
    int* scan_mat = cnt_mat + SCAN_N;
    int* partials = scan_mat + SCAN_N;
    float* nsrc   = (float*)(partials + ((SCAN_NB + 3) & ~3));
    float* ndst   = nsrc + Nn;

    // --- weight transpose+split (tiny) ---
    wtsplit_kernel<256><<<(128 * 256 + 255) / 256, 256, 0, stream>>>(W1, WT1h, WT1l);
    wtsplit_kernel<128><<<(128 * 128 + 255) / 256, 256, 0, stream>>>(W2, WT2h, WT2l);

    // --- CSR + degrees via bucket sort (LDS atomics only) ---
    bucket_count<<<NBLK, 256, 0, stream>>>(esrc, edst, cnt_mat);
    scan_blocks<<<SCAN_NB, 1024, 0, stream>>>(cnt_mat, scan_mat, partials, SCAN_N);
    scan_partials<<<1, 64, 0, stream>>>(partials, SCAN_NB);
    scan_add<<<(SCAN_N + 255) / 256, 256, 0, stream>>>(scan_mat, partials, SCAN_N);
    bucket_scatter<<<NBLK, 256, 0, stream>>>(esrc, edst, scan_mat, tmp);
    finalize_dst<<<NBUCK, 256, 0, stream>>>(tmp, scan_mat, rowptr, csr_src, ndst);
    finalize_src<<<NBUCK, 256, 0, stream>>>(tmp, scan_mat, nsrc);

    const int agg_grid = (Nn * 16 + 255) / 256;

    // --- layer 1: gemm -> h16; aggregate -> d_out (f32 temp) ---
    gemm_mfma<256><<<(Nn + 63) / 64, 256, 0, stream>>>(feat, WT1h, WT1l, nsrc, h16, Nn);
    aggregate_kernel<<<agg_grid, 256, 0, stream>>>(h16, rowptr, csr_src, ndst, b1, out, Nn);

    // --- layer 2: gemm (reads d_out) -> h16; aggregate -> d_out final ---
    gemm_mfma<128><<<(Nn + 63) / 64, 256, 0, stream>>>(out, WT2h, WT2l, nsrc, h16, Nn);
    aggregate_kernel<<<agg_grid, 256, 0, stream>>>(h16, rowptr, csr_src, ndst, b2, out, Nn);
}

// Round 7
// 283.865 us; speedup vs baseline: 20.4708x; 1.0204x over previous
//
#include <hip/hip_runtime.h>
#include <hip/hip_bf16.h>

#define N_NODES 100000
#define N_EDGES 1600000
#define NBUCK 391          // ceil(N_NODES / 256)
#define NBLK 256           // bucket-phase blocks
#define CHUNK (N_EDGES / NBLK)   // 6250, exact
#define MATP (NBUCK * NBLK)      // 100096, per-part count-matrix size

typedef __bf16 bf16x8 __attribute__((ext_vector_type(8)));
typedef float f32x4 __attribute__((ext_vector_type(4)));
typedef unsigned short u16x8 __attribute__((ext_vector_type(8)));
typedef _Float16 f16x8 __attribute__((ext_vector_type(8)));

// ---------------- helpers: f32 -> bf16 (RNE) split ----------------
__device__ __forceinline__ unsigned short f32_to_bf16_rne(float x) {
    unsigned int u = __float_as_uint(x);
    unsigned int r = u + 0x7FFFu + ((u >> 16) & 1u);
    return (unsigned short)(r >> 16);
}
__device__ __forceinline__ float bf16_bits_to_f32(unsigned short h) {
    return __uint_as_float(((unsigned int)h) << 16);
}

// ---------------- phase 1: coarse bucket histograms (LDS atomics only) ----
__global__ __launch_bounds__(256) void bucket_count(const int* __restrict__ esrc,
                                                    const int* __restrict__ edst,
                                                    int* __restrict__ cnt_mat) {
    __shared__ int hd[NBUCK], hs[NBUCK];
    const int b = blockIdx.x, t = threadIdx.x;
    for (int i = t; i < NBUCK; i += 256) { hd[i] = 0; hs[i] = 0; }
    __syncthreads();
    const int e1 = (b + 1) * CHUNK;
    for (int e = b * CHUNK + t; e < e1; e += 256) {
        atomicAdd(&hd[edst[e] >> 8], 1);
        atomicAdd(&hs[esrc[e] >> 8], 1);
    }
    __syncthreads();
    for (int i = t; i < NBUCK; i += 256) {
        cnt_mat[i * NBLK + b] = hd[i];
        cnt_mat[MATP + i * NBLK + b] = hs[i];
    }
}

// ---------------- flat exclusive scan (3-phase) ----------------
__global__ __launch_bounds__(1024) void scan_blocks(const int* __restrict__ counts,
                                                    int* __restrict__ out,
                                                    int* __restrict__ partials, int n) {
    __shared__ int tmp[1024];
    int i = blockIdx.x * 1024 + threadIdx.x;
    int v = (i < n) ? counts[i] : 0;
    tmp[threadIdx.x] = v;
    __syncthreads();
    for (int off = 1; off < 1024; off <<= 1) {
        int t = (threadIdx.x >= (unsigned)off) ? tmp[threadIdx.x - off] : 0;
        __syncthreads();
        tmp[threadIdx.x] += t;
        __syncthreads();
    }
    if (i < n) out[i] = tmp[threadIdx.x] - v;  // exclusive
    if (threadIdx.x == 1023) partials[blockIdx.x] = tmp[1023];
}

__global__ void scan_partials(int* __restrict__ partials, int nb) {
    if (threadIdx.x == 0 && blockIdx.x == 0) {
        int s = 0;
        for (int b = 0; b < nb; ++b) { int t = partials[b]; partials[b] = s; s += t; }
    }
}

__global__ void scan_add(int* __restrict__ data, const int* __restrict__ partials, int n) {
    int i = blockIdx.x * blockDim.x + threadIdx.x;
    if (i < n) data[i] += partials[i >> 10];
}

// ---------------- phase 2: scatter edges into bucket-sorted streams ------
__global__ __launch_bounds__(256) void bucket_scatter(const int* __restrict__ esrc,
                                                      const int* __restrict__ edst,
                                                      const int* __restrict__ scan_mat,
                                                      unsigned int* __restrict__ tmp) {
    __shared__ int cd[NBUCK], cs[NBUCK];
    const int b = blockIdx.x, t = threadIdx.x;
    for (int i = t; i < NBUCK; i += 256) {
        cd[i] = scan_mat[i * NBLK + b];
        cs[i] = scan_mat[MATP + i * NBLK + b];
    }
    __syncthreads();
    const int e1 = (b + 1) * CHUNK;
    for (int e = b * CHUNK + t; e < e1; e += 256) {
        int s = esrc[e], d = edst[e];
        int pd = atomicAdd(&cd[d >> 8], 1);
        tmp[pd] = ((unsigned int)(d & 255) << 17) | (unsigned int)s;
        int ps = atomicAdd(&cs[s >> 8], 1);
        tmp[ps] = (unsigned int)s;
    }
}

// ---------------- phase 3a: per-bucket fine sort -> rowptr, csr_src, ndst -
__global__ __launch_bounds__(256) void finalize_dst(const unsigned int* __restrict__ tmp,
                                                    const int* __restrict__ scan_mat,
                                                    int* __restrict__ rowptr,
                                                    int* __restrict__ csr_src,
                                                    float* __restrict__ ndst) {
    __shared__ int hist[256];
    __shared__ int scn[256];
    __shared__ int cur[256];
    const int b = blockIdx.x, t = threadIdx.x;
    const int beg = scan_mat[b * 256];
    const int end = scan_mat[(b + 1) * 256];
    hist[t] = 0;
    __syncthreads();
    for (int j = beg + t; j < end; j += 256)
        atomicAdd(&hist[tmp[j] >> 17], 1);
    __syncthreads();
    int v = hist[t];
    scn[t] = v;
    __syncthreads();
    for (int off = 1; off < 256; off <<= 1) {
        int u = (t >= off) ? scn[t - off] : 0;
        __syncthreads();
        scn[t] += u;
        __syncthreads();
    }
    int excl = scn[t] - v;
    int node = b * 256 + t;
    if (node <= N_NODES) rowptr[node] = beg + excl;
    if (node < N_NODES) ndst[node] = rsqrtf(fmaxf((float)v, 1.0f));
    cur[t] = beg + excl;
    __syncthreads();
    for (int j = beg + t; j < end; j += 256) {
        unsigned int x = tmp[j];
        int pos = atomicAdd(&cur[x >> 17], 1);
        csr_src[pos] = (int)(x & 0x1FFFFu);
    }
}

// ---------------- phase 3b: per-bucket src histogram -> nsrc -------------
__global__ __launch_bounds__(256) void finalize_src(const unsigned int* __restrict__ tmp,
                                                    const int* __restrict__ scan_mat,
                                                    float* __restrict__ nsrc) {
    __shared__ int hist[256];
    const int b = blockIdx.x, t = threadIdx.x;
    const int beg = scan_mat[MATP + b * 256];
    const int end = (b < NBUCK - 1) ? scan_mat[MATP + (b + 1) * 256] : 2 * N_EDGES;
    hist[t] = 0;
    __syncthreads();
    for (int j = beg + t; j < end; j += 256)
        atomicAdd(&hist[tmp[j] & 255u], 1);
    __syncthreads();
    int node = b * 256 + t;
    if (node < N_NODES) nsrc[node] = rsqrtf(fmaxf((float)hist[t], 1.0f));
}

// ---------------- W -> W^T split into bf16 hi/lo ----------------
template<int K>
__global__ void wtsplit_kernel(const float* __restrict__ W,
                               unsigned short* __restrict__ WTh,
                               unsigned short* __restrict__ WTl) {
    int i = blockIdx.x * blockDim.x + threadIdx.x;
    if (i < 128 * K) {
        int col = i / K, k = i % K;
        float x = W[(size_t)k * 128 + col];
        unsigned short h = f32_to_bf16_rne(x);
        unsigned short l = f32_to_bf16_rne(x - bf16_bits_to_f32(h));
        WTh[i] = h;
        WTl[i] = l;
    }
}

// ---------------- MFMA GEMM (bf16 3-term split), f16 output --------------
// BM=64, BN=128, BK=32; 4 waves (2x2); LDS rows padded to 40 ushorts (80 B)
template<int K>
__global__ __launch_bounds__(256) void gemm_mfma(
    const float* __restrict__ A,            // [M, K] f32
    const unsigned short* __restrict__ WTh, // [128][K] bf16 hi
    const unsigned short* __restrict__ WTl, // [128][K] bf16 lo
    const float* __restrict__ rowscale,     // [M]
    _Float16* __restrict__ C16,             // [M, 128] f16 out
    int M)
{
    constexpr int LDA = 40;  // padded row stride in ushorts (80 B)
    __shared__ unsigned short Ah[64 * LDA];
    __shared__ unsigned short Al[64 * LDA];
    __shared__ unsigned short Bh[128 * LDA];
    __shared__ unsigned short Bl[128 * LDA];

    const int tid = threadIdx.x;
    const int bm = blockIdx.x * 64;
    const int lane = tid & 63;
    const int wid = tid >> 6;
    const int wm = wid >> 1;         // 0..1: 32-row half
    const int wn = wid & 1;          // 0..1: 64-col half
    const int lr = lane & 15;
    const int lg = lane >> 4;

    const int st_ar = tid >> 2;
    const int st_s8 = tid & 3;
    const int a_row_g = bm + st_ar;

    f32x4 acc[2][4];
    #pragma unroll
    for (int i = 0; i < 2; ++i)
        #pragma unroll
        for (int j = 0; j < 4; ++j)
            acc[i][j] = (f32x4){0.f, 0.f, 0.f, 0.f};

    float4 av0, av1;
    u16x8 bvh[2], bvl[2];

    auto load_tile = [&](int k0) {
        if (a_row_g < M) {
            const float* ap = &A[(size_t)a_row_g * K + k0 + st_s8 * 8];
            av0 = *reinterpret_cast<const float4*>(ap);
            av1 = *reinterpret_cast<const float4*>(ap + 4);
        } else {
            av0 = make_float4(0.f, 0.f, 0.f, 0.f);
            av1 = make_float4(0.f, 0.f, 0.f, 0.f);
        }
        #pragma unroll
        for (int i = 0; i < 2; ++i) {
            int lin = tid + i * 256;
            int col = lin >> 2;
            int s8  = lin & 3;
            const size_t g = (size_t)col * K + k0 + s8 * 8;
            bvh[i] = *reinterpret_cast<const u16x8*>(&WTh[g]);
            bvl[i] = *reinterpret_cast<const u16x8*>(&WTl[g]);
        }
    };

    load_tile(0);

    for (int k0 = 0; k0 < K; k0 += 32) {
        {
            float v[8] = {av0.x, av0.y, av0.z, av0.w, av1.x, av1.y, av1.z, av1.w};
            u16x8 vh, vl;
            #pragma unroll
            for (int j = 0; j < 8; ++j) {
                unsigned short h = f32_to_bf16_rne(v[j]);
                vh[j] = h;
                vl[j] = f32_to_bf16_rne(v[j] - bf16_bits_to_f32(h));
            }
            int off = st_ar * LDA + st_s8 * 8;
            *reinterpret_cast<u16x8*>(&Ah[off]) = vh;
            *reinterpret_cast<u16x8*>(&Al[off]) = vl;
            #pragma unroll
            for (int i = 0; i < 2; ++i) {
                int lin = tid + i * 256;
                int col = lin >> 2;
                int s8  = lin & 3;
                int boff = col * LDA + s8 * 8;
                *reinterpret_cast<u16x8*>(&Bh[boff]) = bvh[i];
                *reinterpret_cast<u16x8*>(&Bl[boff]) = bvl[i];
            }
        }
        __syncthreads();

        if (k0 + 32 < K) load_tile(k0 + 32);

        {
            bf16x8 afh[2], afl[2], bfh[4], bfl[4];
            #pragma unroll
            for (int mt = 0; mt < 2; ++mt) {
                int row = wm * 32 + mt * 16 + lr;
                int off = row * LDA + lg * 8;
                afh[mt] = *reinterpret_cast<const bf16x8*>(&Ah[off]);
                afl[mt] = *reinterpret_cast<const bf16x8*>(&Al[off]);
            }
            #pragma unroll
            for (int nt = 0; nt < 4; ++nt) {
                int col = wn * 64 + nt * 16 + lr;
                int off = col * LDA + lg * 8;
                bfh[nt] = *reinterpret_cast<const bf16x8*>(&Bh[off]);
                bfl[nt] = *reinterpret_cast<const bf16x8*>(&Bl[off]);
            }
            #pragma unroll
            for (int mt = 0; mt < 2; ++mt) {
                #pragma unroll
                for (int nt = 0; nt < 4; ++nt) {
                    acc[mt][nt] = __builtin_amdgcn_mfma_f32_16x16x32_bf16(
                        afh[mt], bfh[nt], acc[mt][nt], 0, 0, 0);
                    acc[mt][nt] = __builtin_amdgcn_mfma_f32_16x16x32_bf16(
                        afh[mt], bfl[nt], acc[mt][nt], 0, 0, 0);
                    acc[mt][nt] = __builtin_amdgcn_mfma_f32_16x16x32_bf16(
                        afl[mt], bfh[nt], acc[mt][nt], 0, 0, 0);
                }
            }
        }
        __syncthreads();
    }

    #pragma unroll
    for (int mt = 0; mt < 2; ++mt) {
        #pragma unroll
        for (int r = 0; r < 4; ++r) {
            int row = bm + wm * 32 + mt * 16 + lg * 4 + r;
            if (row < M) {
                float s = rowscale[row];
                #pragma unroll
                for (int nt = 0; nt < 4; ++nt) {
                    int col = wn * 64 + nt * 16 + lr;
                    C16[(size_t)row * 128 + col] = (_Float16)(acc[mt][nt][r] * s);
                }
            }
        }
    }
}

// ---------------- CSR aggregation over f16 rows, fused epilogue ----------
// 16 lanes per node, 8 cols each; 4-wide gather unroll for MLP.
__global__ __launch_bounds__(256) void aggregate_kernel(
    const _Float16* __restrict__ h16,
    const int* __restrict__ rowptr,
    const int* __restrict__ csr_src,
    const float* __restrict__ ndst,
    const float* __restrict__ bias,
    float* __restrict__ out, int N)
{
    int g = blockIdx.x * blockDim.x + threadIdx.x;
    int node = g >> 4;
    if (node >= N) return;
    int c8 = (g & 15) * 8;
    int beg = rowptr[node];
    int end = rowptr[node + 1];
    float acc[8] = {0.f, 0.f, 0.f, 0.f, 0.f, 0.f, 0.f, 0.f};
    int j = beg;
    for (; j + 3 < end; j += 4) {
        // issue all 4 index loads (independent), then 4 independent gathers
        int s0 = csr_src[j];
        int s1 = csr_src[j + 1];
        int s2 = csr_src[j + 2];
        int s3 = csr_src[j + 3];
        f16x8 v0 = *reinterpret_cast<const f16x8*>(&h16[(size_t)s0 * 128 + c8]);
        f16x8 v1 = *reinterpret_cast<const f16x8*>(&h16[(size_t)s1 * 128 + c8]);
        f16x8 v2 = *reinterpret_cast<const f16x8*>(&h16[(size_t)s2 * 128 + c8]);
        f16x8 v3 = *reinterpret_cast<const f16x8*>(&h16[(size_t)s3 * 128 + c8]);
        #pragma unroll
        for (int k = 0; k < 8; ++k)
            acc[k] += ((float)v0[k] + (float)v1[k]) + ((float)v2[k] + (float)v3[k]);
    }
    for (; j < end; ++j) {
        int s0 = csr_src[j];
        f16x8 v0 = *reinterpret_cast<const f16x8*>(&h16[(size_t)s0 * 128 + c8]);
        #pragma unroll
        for (int k = 0; k < 8; ++k) acc[k] += (float)v0[k];
    }
    float sc = ndst[node];
    const float4 b0 = *reinterpret_cast<const float4*>(&bias[c8]);
    const float4 b1 = *reinterpret_cast<const float4*>(&bias[c8 + 4]);
    float4 r0, r1;
    r0.x = fmaxf(acc[0] * sc + b0.x, 0.f);
    r0.y = fmaxf(acc[1] * sc + b0.y, 0.f);
    r0.z = fmaxf(acc[2] * sc + b0.z, 0.f);
    r0.w = fmaxf(acc[3] * sc + b0.w, 0.f);
    r1.x = fmaxf(acc[4] * sc + b1.x, 0.f);
    r1.y = fmaxf(acc[5] * sc + b1.y, 0.f);
    r1.z = fmaxf(acc[6] * sc + b1.z, 0.f);
    r1.w = fmaxf(acc[7] * sc + b1.w, 0.f);
    float* op = &out[(size_t)node * 128 + c8];
    *reinterpret_cast<float4*>(op) = r0;
    *reinterpret_cast<float4*>(op + 4) = r1;
}

extern "C" void kernel_launch(void* const* d_in, const int* in_sizes, int n_in,
                              void* d_out, int out_size, void* d_ws, size_t ws_size,
                              hipStream_t stream) {
    const float* feat = (const float*)d_in[0];   // [1, N, 256]
    const float* W1   = (const float*)d_in[1];   // [256, 128]
    const float* b1   = (const float*)d_in[2];   // [128]
    const float* W2   = (const float*)d_in[3];   // [128, 128]
    const float* b2   = (const float*)d_in[4];   // [128]
    const int* esrc   = (const int*)d_in[5];     // [E]
    const int* edst   = (const int*)d_in[6];     // [E]
    float* out = (float*)d_out;                  // [N, 128]

    const int Nn = N_NODES, E = N_EDGES;
    const int SCAN_N = 2 * MATP;                 // 200192
    const int SCAN_NB = (SCAN_N + 1023) / 1024;  // 196

    float* hseg   = (float*)d_ws;
    _Float16* h16 = (_Float16*)hseg;
    unsigned short* WT1h = (unsigned short*)(hseg + (size_t)Nn * 128);
    unsigned short* WT1l = WT1h + 128 * 256;
    unsigned short* WT2h = WT1l + 128 * 256;
    unsigned short* WT2l = WT2h + 128 * 128;
    int* csr_src  = (int*)(WT2l + 128 * 128);
    int* rowptr   = csr_src + E;
    unsigned int* tmp = (unsigned int*)(rowptr + 100004);
    int* cnt_mat  = (int*)(tmp + 2 * (size_t)E);
    int* scan_mat = cnt_mat + SCAN_N;
    int* partials = scan_mat + SCAN_N;
    float* nsrc   = (float*)(partials + ((SCAN_NB + 3) & ~3));
    float* ndst   = nsrc + Nn;

    // --- weight transpose+split (tiny) ---
    wtsplit_kernel<256><<<(128 * 256 + 255) / 256, 256, 0, stream>>>(W1, WT1h, WT1l);
    wtsplit_kernel<128><<<(128 * 128 + 255) / 256, 256, 0, stream>>>(W2, WT2h, WT2l);

    // --- CSR + degrees via bucket sort (LDS atomics only) ---
    bucket_count<<<NBLK, 256, 0, stream>>>(esrc, edst, cnt_mat);
    scan_blocks<<<SCAN_NB, 1024, 0, stream>>>(cnt_mat, scan_mat, partials, SCAN_N);
    scan_partials<<<1, 64, 0, stream>>>(partials, SCAN_NB);
    scan_add<<<(SCAN_N + 255) / 256, 256, 0, stream>>>(scan_mat, partials, SCAN_N);
    bucket_scatter<<<NBLK, 256, 0, stream>>>(esrc, edst, scan_mat, tmp);
    finalize_dst<<<NBUCK, 256, 0, stream>>>(tmp, scan_mat, rowptr, csr_src, ndst);
    finalize_src<<<NBUCK, 256, 0, stream>>>(tmp, scan_mat, nsrc);

    const int agg_grid = (Nn * 16 + 255) / 256;

    // --- layer 1: gemm -> h16; aggregate -> d_out (f32 temp) ---
    gemm_mfma<256><<<(Nn + 63) / 64, 256, 0, stream>>>(feat, WT1h, WT1l, nsrc, h16, Nn);
    aggregate_kernel<<<agg_grid, 256, 0, stream>>>(h16, rowptr, csr_src, ndst, b1, out, Nn);

    // --- layer 2: gemm (reads d_out) -> h16; aggregate -> d_out final ---
    gemm_mfma<128><<<(Nn + 63) / 64, 256, 0, stream>>>(out, WT2h, WT2l, nsrc, h16, Nn);
    aggregate_kernel<<<agg_grid, 256, 0, stream>>>(h16, rowptr, csr_src, ndst, b2, out, Nn);
}

// Round 8
// 280.510 us; speedup vs baseline: 20.7156x; 1.0120x over previous
//
#include <hip/hip_runtime.h>
#include <hip/hip_bf16.h>

#define N_NODES 100000
#define N_EDGES 1600000
#define NBUCK 391          // ceil(N_NODES / 256)
#define NBLK 256           // bucket-phase blocks
#define CHUNK (N_EDGES / NBLK)   // 6250, exact
#define MATP (NBUCK * NBLK)      // 100096, per-part count-matrix size

typedef __bf16 bf16x8 __attribute__((ext_vector_type(8)));
typedef float f32x4 __attribute__((ext_vector_type(4)));
typedef unsigned short u16x8 __attribute__((ext_vector_type(8)));
typedef _Float16 f16x8 __attribute__((ext_vector_type(8)));

// ---------------- helpers: f32 -> bf16 (RNE) split ----------------
__device__ __forceinline__ unsigned short f32_to_bf16_rne(float x) {
    unsigned int u = __float_as_uint(x);
    unsigned int r = u + 0x7FFFu + ((u >> 16) & 1u);
    return (unsigned short)(r >> 16);
}
__device__ __forceinline__ float bf16_bits_to_f32(unsigned short h) {
    return __uint_as_float(((unsigned int)h) << 16);
}

__device__ __forceinline__ void wtsplit_elem(const float* __restrict__ W,
                                             unsigned short* __restrict__ WTh,
                                             unsigned short* __restrict__ WTl,
                                             int K, int i) {
    int col = i / K, k = i - col * K;
    float x = W[(size_t)k * 128 + col];
    unsigned short h = f32_to_bf16_rne(x);
    unsigned short l = f32_to_bf16_rne(x - bf16_bits_to_f32(h));
    WTh[i] = h;
    WTl[i] = l;
}

// ---------------- fused setup: bucket histograms + weight transpose/split --
// blocks [0,NBLK): bucket_count ; blocks [NBLK, NBLK+192): wtsplit W1/W2
__global__ __launch_bounds__(256) void fused_setup(
    const int* __restrict__ esrc, const int* __restrict__ edst,
    int* __restrict__ cnt_mat,
    const float* __restrict__ W1, unsigned short* __restrict__ WT1h,
    unsigned short* __restrict__ WT1l,
    const float* __restrict__ W2, unsigned short* __restrict__ WT2h,
    unsigned short* __restrict__ WT2l)
{
    __shared__ int hd[NBUCK], hs[NBUCK];
    const int b = blockIdx.x, t = threadIdx.x;
    if (b < NBLK) {
        for (int i = t; i < NBUCK; i += 256) { hd[i] = 0; hs[i] = 0; }
        __syncthreads();
        const int e1 = (b + 1) * CHUNK;
        for (int e = b * CHUNK + t; e < e1; e += 256) {
            atomicAdd(&hd[edst[e] >> 8], 1);
            atomicAdd(&hs[esrc[e] >> 8], 1);
        }
        __syncthreads();
        for (int i = t; i < NBUCK; i += 256) {
            cnt_mat[i * NBLK + b] = hd[i];
            cnt_mat[MATP + i * NBLK + b] = hs[i];
        }
    } else {
        int i = (b - NBLK) * 256 + t;         // 0..49151
        if (i < 128 * 256) {
            wtsplit_elem(W1, WT1h, WT1l, 256, i);
        } else {
            int j = i - 128 * 256;            // < 16384
            wtsplit_elem(W2, WT2h, WT2l, 128, j);
        }
    }
}

// ---------------- flat exclusive scan (2 kernels; partials applied inline) -
__global__ __launch_bounds__(1024) void scan_blocks(const int* __restrict__ counts,
                                                    int* __restrict__ out,
                                                    int* __restrict__ partials, int n) {
    __shared__ int tmp[1024];
    int i = blockIdx.x * 1024 + threadIdx.x;
    int v = (i < n) ? counts[i] : 0;
    tmp[threadIdx.x] = v;
    __syncthreads();
    for (int off = 1; off < 1024; off <<= 1) {
        int t = (threadIdx.x >= (unsigned)off) ? tmp[threadIdx.x - off] : 0;
        __syncthreads();
        tmp[threadIdx.x] += t;
        __syncthreads();
    }
    if (i < n) out[i] = tmp[threadIdx.x] - v;  // exclusive (within block)
    if (threadIdx.x == 1023) partials[blockIdx.x] = tmp[1023];
}

__global__ void scan_partials(int* __restrict__ partials, int nb) {
    if (threadIdx.x == 0 && blockIdx.x == 0) {
        int s = 0;
        for (int b = 0; b < nb; ++b) { int t = partials[b]; partials[b] = s; s += t; }
    }
}

// global exclusive prefix at index i
__device__ __forceinline__ int sm_at(const int* __restrict__ scan_mat,
                                     const int* __restrict__ partials, int i) {
    return scan_mat[i] + partials[i >> 10];
}

// ---------------- phase 2: scatter edges into bucket-sorted streams ------
__global__ __launch_bounds__(256) void bucket_scatter(const int* __restrict__ esrc,
                                                      const int* __restrict__ edst,
                                                      const int* __restrict__ scan_mat,
                                                      const int* __restrict__ partials,
                                                      unsigned int* __restrict__ tmp) {
    __shared__ int cd[NBUCK], cs[NBUCK];
    const int b = blockIdx.x, t = threadIdx.x;
    for (int i = t; i < NBUCK; i += 256) {
        cd[i] = sm_at(scan_mat, partials, i * NBLK + b);
        cs[i] = sm_at(scan_mat, partials, MATP + i * NBLK + b);
    }
    __syncthreads();
    const int e1 = (b + 1) * CHUNK;
    for (int e = b * CHUNK + t; e < e1; e += 256) {
        int s = esrc[e], d = edst[e];
        int pd = atomicAdd(&cd[d >> 8], 1);
        tmp[pd] = ((unsigned int)(d & 255) << 17) | (unsigned int)s;
        int ps = atomicAdd(&cs[s >> 8], 1);
        tmp[ps] = (unsigned int)s;
    }
}

// ---------------- phase 3: fused per-bucket finalize (dst + src) ---------
// blocks [0,NBUCK): dst -> rowptr, csr_src, ndst ; [NBUCK,2*NBUCK): src -> nsrc
__global__ __launch_bounds__(256) void finalize_fused(
    const unsigned int* __restrict__ tmp,
    const int* __restrict__ scan_mat,
    const int* __restrict__ partials,
    int* __restrict__ rowptr,
    int* __restrict__ csr_src,
    float* __restrict__ ndst,
    float* __restrict__ nsrc)
{
    __shared__ int hist[256];
    __shared__ int scn[256];
    __shared__ int cur[256];
    const int bb = blockIdx.x, t = threadIdx.x;
    if (bb < NBUCK) {
        const int b = bb;
        const int beg = sm_at(scan_mat, partials, b * 256);
        const int end = sm_at(scan_mat, partials, (b + 1) * 256);  // b=NBUCK-1 -> =E
        hist[t] = 0;
        __syncthreads();
        for (int j = beg + t; j < end; j += 256)
            atomicAdd(&hist[tmp[j] >> 17], 1);
        __syncthreads();
        int v = hist[t];
        scn[t] = v;
        __syncthreads();
        for (int off = 1; off < 256; off <<= 1) {
            int u = (t >= off) ? scn[t - off] : 0;
            __syncthreads();
            scn[t] += u;
            __syncthreads();
        }
        int excl = scn[t] - v;
        int node = b * 256 + t;
        if (node <= N_NODES) rowptr[node] = beg + excl;
        if (node < N_NODES) ndst[node] = rsqrtf(fmaxf((float)v, 1.0f));
        cur[t] = beg + excl;
        __syncthreads();
        for (int j = beg + t; j < end; j += 256) {
            unsigned int x = tmp[j];
            int pos = atomicAdd(&cur[x >> 17], 1);
            csr_src[pos] = (int)(x & 0x1FFFFu);
        }
    } else {
        const int b = bb - NBUCK;
        const int beg = sm_at(scan_mat, partials, MATP + b * 256);
        const int end = (b < NBUCK - 1) ? sm_at(scan_mat, partials, MATP + (b + 1) * 256)
                                        : 2 * N_EDGES;
        hist[t] = 0;
        __syncthreads();
        for (int j = beg + t; j < end; j += 256)
            atomicAdd(&hist[tmp[j] & 255u], 1);
        __syncthreads();
        int node = b * 256 + t;
        if (node < N_NODES) nsrc[node] = rsqrtf(fmaxf((float)hist[t], 1.0f));
    }
}

// ---------------- MFMA GEMM (bf16 3-term split), f16 output --------------
// BM=64, BN=128, BK=32; 4 waves (2x2); LDS rows padded to 40 ushorts (80 B)
template<int K>
__global__ __launch_bounds__(256) void gemm_mfma(
    const float* __restrict__ A,            // [M, K] f32
    const unsigned short* __restrict__ WTh, // [128][K] bf16 hi
    const unsigned short* __restrict__ WTl, // [128][K] bf16 lo
    const float* __restrict__ rowscale,     // [M]
    _Float16* __restrict__ C16,             // [M, 128] f16 out
    int M)
{
    constexpr int LDA = 40;  // padded row stride in ushorts (80 B)
    __shared__ unsigned short Ah[64 * LDA];
    __shared__ unsigned short Al[64 * LDA];
    __shared__ unsigned short Bh[128 * LDA];
    __shared__ unsigned short Bl[128 * LDA];

    const int tid = threadIdx.x;
    const int bm = blockIdx.x * 64;
    const int lane = tid & 63;
    const int wid = tid >> 6;
    const int wm = wid >> 1;
    const int wn = wid & 1;
    const int lr = lane & 15;
    const int lg = lane >> 4;

    const int st_ar = tid >> 2;
    const int st_s8 = tid & 3;
    const int a_row_g = bm + st_ar;

    f32x4 acc[2][4];
    #pragma unroll
    for (int i = 0; i < 2; ++i)
        #pragma unroll
        for (int j = 0; j < 4; ++j)
            acc[i][j] = (f32x4){0.f, 0.f, 0.f, 0.f};

    float4 av0, av1;
    u16x8 bvh[2], bvl[2];

    auto load_tile = [&](int k0) {
        if (a_row_g < M) {
            const float* ap = &A[(size_t)a_row_g * K + k0 + st_s8 * 8];
            av0 = *reinterpret_cast<const float4*>(ap);
            av1 = *reinterpret_cast<const float4*>(ap + 4);
        } else {
            av0 = make_float4(0.f, 0.f, 0.f, 0.f);
            av1 = make_float4(0.f, 0.f, 0.f, 0.f);
        }
        #pragma unroll
        for (int i = 0; i < 2; ++i) {
            int lin = tid + i * 256;
            int col = lin >> 2;
            int s8  = lin & 3;
            const size_t g = (size_t)col * K + k0 + s8 * 8;
            bvh[i] = *reinterpret_cast<const u16x8*>(&WTh[g]);
            bvl[i] = *reinterpret_cast<const u16x8*>(&WTl[g]);
        }
    };

    load_tile(0);

    for (int k0 = 0; k0 < K; k0 += 32) {
        {
            float v[8] = {av0.x, av0.y, av0.z, av0.w, av1.x, av1.y, av1.z, av1.w};
            u16x8 vh, vl;
            #pragma unroll
            for (int j = 0; j < 8; ++j) {
                unsigned short h = f32_to_bf16_rne(v[j]);
                vh[j] = h;
                vl[j] = f32_to_bf16_rne(v[j] - bf16_bits_to_f32(h));
            }
            int off = st_ar * LDA + st_s8 * 8;
            *reinterpret_cast<u16x8*>(&Ah[off]) = vh;
            *reinterpret_cast<u16x8*>(&Al[off]) = vl;
            #pragma unroll
            for (int i = 0; i < 2; ++i) {
                int lin = tid + i * 256;
                int col = lin >> 2;
                int s8  = lin & 3;
                int boff = col * LDA + s8 * 8;
                *reinterpret_cast<u16x8*>(&Bh[boff]) = bvh[i];
                *reinterpret_cast<u16x8*>(&Bl[boff]) = bvl[i];
            }
        }
        __syncthreads();

        if (k0 + 32 < K) load_tile(k0 + 32);

        {
            bf16x8 afh[2], afl[2], bfh[4], bfl[4];
            #pragma unroll
            for (int mt = 0; mt < 2; ++mt) {
                int row = wm * 32 + mt * 16 + lr;
                int off = row * LDA + lg * 8;
                afh[mt] = *reinterpret_cast<const bf16x8*>(&Ah[off]);
                afl[mt] = *reinterpret_cast<const bf16x8*>(&Al[off]);
            }
            #pragma unroll
            for (int nt = 0; nt < 4; ++nt) {
                int col = wn * 64 + nt * 16 + lr;
                int off = col * LDA + lg * 8;
                bfh[nt] = *reinterpret_cast<const bf16x8*>(&Bh[off]);
                bfl[nt] = *reinterpret_cast<const bf16x8*>(&Bl[off]);
            }
            #pragma unroll
            for (int mt = 0; mt < 2; ++mt) {
                #pragma unroll
                for (int nt = 0; nt < 4; ++nt) {
                    acc[mt][nt] = __builtin_amdgcn_mfma_f32_16x16x32_bf16(
                        afh[mt], bfh[nt], acc[mt][nt], 0, 0, 0);
                    acc[mt][nt] = __builtin_amdgcn_mfma_f32_16x16x32_bf16(
                        afh[mt], bfl[nt], acc[mt][nt], 0, 0, 0);
                    acc[mt][nt] = __builtin_amdgcn_mfma_f32_16x16x32_bf16(
                        afl[mt], bfh[nt], acc[mt][nt], 0, 0, 0);
                }
            }
        }
        __syncthreads();
    }

    #pragma unroll
    for (int mt = 0; mt < 2; ++mt) {
        #pragma unroll
        for (int r = 0; r < 4; ++r) {
            int row = bm + wm * 32 + mt * 16 + lg * 4 + r;
            if (row < M) {
                float s = rowscale[row];
                #pragma unroll
                for (int nt = 0; nt < 4; ++nt) {
                    int col = wn * 64 + nt * 16 + lr;
                    C16[(size_t)row * 128 + col] = (_Float16)(acc[mt][nt][r] * s);
                }
            }
        }
    }
}

// ---------------- CSR aggregation, column-split half (64 cols/pass) ------
// 8 lanes per node, 8 cols each; 4-wide gather unroll.
__global__ __launch_bounds__(256) void aggregate_half(
    const _Float16* __restrict__ h16,
    const int* __restrict__ rowptr,
    const int* __restrict__ csr_src,
    const float* __restrict__ ndst,
    const float* __restrict__ bias,
    float* __restrict__ out, int N, int c_base)
{
    int g = blockIdx.x * blockDim.x + threadIdx.x;
    int node = g >> 3;
    if (node >= N) return;
    int c8 = ((g & 7) * 8) + c_base;
    int beg = rowptr[node];
    int end = rowptr[node + 1];
    float acc[8] = {0.f, 0.f, 0.f, 0.f, 0.f, 0.f, 0.f, 0.f};
    int j = beg;
    for (; j + 3 < end; j += 4) {
        int s0 = csr_src[j];
        int s1 = csr_src[j + 1];
        int s2 = csr_src[j + 2];
        int s3 = csr_src[j + 3];
        f16x8 v0 = *reinterpret_cast<const f16x8*>(&h16[(size_t)s0 * 128 + c8]);
        f16x8 v1 = *reinterpret_cast<const f16x8*>(&h16[(size_t)s1 * 128 + c8]);
        f16x8 v2 = *reinterpret_cast<const f16x8*>(&h16[(size_t)s2 * 128 + c8]);
        f16x8 v3 = *reinterpret_cast<const f16x8*>(&h16[(size_t)s3 * 128 + c8]);
        #pragma unroll
        for (int k = 0; k < 8; ++k)
            acc[k] += ((float)v0[k] + (float)v1[k]) + ((float)v2[k] + (float)v3[k]);
    }
    for (; j < end; ++j) {
        int s0 = csr_src[j];
        f16x8 v0 = *reinterpret_cast<const f16x8*>(&h16[(size_t)s0 * 128 + c8]);
        #pragma unroll
        for (int k = 0; k < 8; ++k) acc[k] += (float)v0[k];
    }
    float sc = ndst[node];
    const float4 b0 = *reinterpret_cast<const float4*>(&bias[c8]);
    const float4 b1 = *reinterpret_cast<const float4*>(&bias[c8 + 4]);
    float4 r0, r1;
    r0.x = fmaxf(acc[0] * sc + b0.x, 0.f);
    r0.y = fmaxf(acc[1] * sc + b0.y, 0.f);
    r0.z = fmaxf(acc[2] * sc + b0.z, 0.f);
    r0.w = fmaxf(acc[3] * sc + b0.w, 0.f);
    r1.x = fmaxf(acc[4] * sc + b1.x, 0.f);
    r1.y = fmaxf(acc[5] * sc + b1.y, 0.f);
    r1.z = fmaxf(acc[6] * sc + b1.z, 0.f);
    r1.w = fmaxf(acc[7] * sc + b1.w, 0.f);
    float* op = &out[(size_t)node * 128 + c8];
    *reinterpret_cast<float4*>(op) = r0;
    *reinterpret_cast<float4*>(op + 4) = r1;
}

extern "C" void kernel_launch(void* const* d_in, const int* in_sizes, int n_in,
                              void* d_out, int out_size, void* d_ws, size_t ws_size,
                              hipStream_t stream) {
    const float* feat = (const float*)d_in[0];   // [1, N, 256]
    const float* W1   = (const float*)d_in[1];   // [256, 128]
    const float* b1   = (const float*)d_in[2];   // [128]
    const float* W2   = (const float*)d_in[3];   // [128, 128]
    const float* b2   = (const float*)d_in[4];   // [128]
    const int* esrc   = (const int*)d_in[5];     // [E]
    const int* edst   = (const int*)d_in[6];     // [E]
    float* out = (float*)d_out;                  // [N, 128]

    const int Nn = N_NODES, E = N_EDGES;
    const int SCAN_N = 2 * MATP;                 // 200192
    const int SCAN_NB = (SCAN_N + 1023) / 1024;  // 196

    float* hseg   = (float*)d_ws;
    _Float16* h16 = (_Float16*)hseg;
    unsigned short* WT1h = (unsigned short*)(hseg + (size_t)Nn * 128);
    unsigned short* WT1l = WT1h + 128 * 256;
    unsigned short* WT2h = WT1l + 128 * 256;
    unsigned short* WT2l = WT2h + 128 * 128;
    int* csr_src  = (int*)(WT2l + 128 * 128);
    int* rowptr   = csr_src + E;
    unsigned int* tmp = (unsigned int*)(rowptr + 100004);
    int* cnt_mat  = (int*)(tmp + 2 * (size_t)E);
    int* scan_mat = cnt_mat + SCAN_N;
    int* partials = scan_mat + SCAN_N;
    float* nsrc   = (float*)(partials + ((SCAN_NB + 3) & ~3));
    float* ndst   = nsrc + Nn;

    // --- setup: bucket histograms + weight transpose/split (fused) ---
    fused_setup<<<NBLK + 192, 256, 0, stream>>>(esrc, edst, cnt_mat,
                                                W1, WT1h, WT1l, W2, WT2h, WT2l);

    // --- scan (partials applied inline downstream) ---
    scan_blocks<<<SCAN_NB, 1024, 0, stream>>>(cnt_mat, scan_mat, partials, SCAN_N);
    scan_partials<<<1, 64, 0, stream>>>(partials, SCAN_NB);

    // --- scatter + fused finalize ---
    bucket_scatter<<<NBLK, 256, 0, stream>>>(esrc, edst, scan_mat, partials, tmp);
    finalize_fused<<<2 * NBUCK, 256, 0, stream>>>(tmp, scan_mat, partials,
                                                  rowptr, csr_src, ndst, nsrc);

    const int aggh_grid = (Nn * 8 + 255) / 256;  // 3125

    // --- layer 1: gemm -> h16; aggregate (2 column passes) -> d_out ---
    gemm_mfma<256><<<(Nn + 63) / 64, 256, 0, stream>>>(feat, WT1h, WT1l, nsrc, h16, Nn);
    aggregate_half<<<aggh_grid, 256, 0, stream>>>(h16, rowptr, csr_src, ndst, b1, out, Nn, 0);
    aggregate_half<<<aggh_grid, 256, 0, stream>>>(h16, rowptr, csr_src, ndst, b1, out, Nn, 64);

    // --- layer 2: gemm (reads d_out) -> h16; aggregate (2 passes) -> d_out ---
    gemm_mfma<128><<<(Nn + 63) / 64, 256, 0, stream>>>(out, WT2h, WT2l, nsrc, h16, Nn);
    aggregate_half<<<aggh_grid, 256, 0, stream>>>(h16, rowptr, csr_src, ndst, b2, out, Nn, 0);
    aggregate_half<<<aggh_grid, 256, 0, stream>>>(h16, rowptr, csr_src, ndst, b2, out, Nn, 64);
}